// Round 7
// baseline (707.334 us; speedup 1.0000x reference)
//
#include <hip/hip_runtime.h>
#include <hip/hip_bf16.h>
#include <cmath>

#define NN 49920
#define EE 200000
#define BB 128

typedef __attribute__((ext_vector_type(8))) short short8;
typedef __attribute__((ext_vector_type(4))) float floatx4;
typedef __attribute__((ext_vector_type(2))) float float2v;

union u8x16 { short8 v; unsigned short u[8]; };

__device__ __forceinline__ float bits2f(unsigned short u) {
    union { unsigned int i; float f; } c; c.i = ((unsigned int)u) << 16; return c.f;
}
__device__ __forceinline__ unsigned short f2bits(float f) {
    union { float f; unsigned int i; } c; c.f = f;
    unsigned int x = c.i;
    return (unsigned short)((x + 0x7fffu + ((x >> 16) & 1u)) >> 16);   // RNE
}
__device__ __forceinline__ unsigned short f2bits_trunc(float f) {
    union { float f; unsigned int i; } c; c.f = f;
    return (unsigned short)(c.i >> 16);                               // truncate (1 op)
}
__device__ __forceinline__ float2v cvt2(unsigned int w) {
    union { unsigned int i; float f; } lo, hi;
    lo.i = w << 16; hi.i = w & 0xffff0000u;
    return (float2v){lo.f, hi.f};
}
// exact leaky_relu(v) = max(v, 0.2v)
__device__ __forceinline__ float2v lrelu2(float2v v) {
    float2v t = v * 0.2f;
    return (float2v){fmaxf(v.x, t.x), fmaxf(v.y, t.y)};
}

typedef const __attribute__((address_space(1))) void* gvp;
typedef __attribute__((address_space(3))) void* lvp;
__device__ __forceinline__ void gll16(const void* g, void* l) {
    __builtin_amdgcn_global_load_lds((gvp)g, (lvp)l, 16, 0, 0);
}

// ---------------- small utility kernels ----------------
__global__ void zero_int_kernel(int* __restrict__ p, int n) {
    int i = blockIdx.x * blockDim.x + threadIdx.x;
    if (i < n) p[i] = 0;
}

__global__ void convert_bf16_kernel(const float* __restrict__ src, unsigned short* __restrict__ dst, int n) {
    int i = blockIdx.x * blockDim.x + threadIdx.x;
    if (i < n) dst[i] = f2bits(src[i]);
}

// fused conversion of ALL weights
__global__ void convert_weights_kernel(
    const float* __restrict__ Wl1, const float* __restrict__ Wr1,
    const float* __restrict__ Wl2, const float* __restrict__ Wr2,
    const float* __restrict__ We1, const float* __restrict__ We2,
    const float* __restrict__ bl2, const float* __restrict__ br2,
    unsigned short* __restrict__ wtl1, unsigned short* __restrict__ wtr1,
    unsigned short* __restrict__ wtlr2, unsigned short* __restrict__ weT1,
    unsigned short* __restrict__ weT2, float* __restrict__ blr2) {
    int b = blockIdx.x, tid = threadIdx.x;
    if (b < 1024) {                       // Wl1/Wr1 [128][1024] -> WT [1024][128]
        const float* W = (b < 512) ? Wl1 : Wr1;
        unsigned short* WT = (b < 512) ? wtl1 : wtr1;
        int i = ((b & 511) << 8) + tid;
        int n = i >> 7, k = i & 127;
        WT[i] = f2bits(W[k * 1024 + n]);
    } else if (b < 3072) {                // Wl2/Wr2 [1024][256] -> wtlr2 [512][1024]
        int bb = b - 1024;
        const float* W = (bb < 1024) ? Wl2 : Wr2;
        int i = ((bb & 1023) << 8) + tid;
        int n = i >> 10, k = i & 1023;
        int off = (bb < 1024) ? 0 : 262144;
        wtlr2[off + i] = f2bits(W[k * 256 + n]);
    } else if (b < 3136) {                // We1 [16][1024] -> weT1 [1024][16]
        int i = ((b - 3072) << 8) + tid;
        int col = i >> 4, k = i & 15;
        weT1[i] = f2bits(We1[k * 1024 + col]);
    } else if (b < 3152) {                // We2 [16][256] -> weT2 [256][16]
        int i = ((b - 3136) << 8) + tid;
        int col = i >> 4, k = i & 15;
        weT2[i] = f2bits(We2[k * 256 + col]);
    } else {                              // blr2 = bl2 | br2 (512 f32)
        int i = ((b - 3152) << 8) + tid;
        if (i < 512) blr2[i] = (i < 256) ? bl2[i] : br2[i - 256];
    }
}

// ---------------- bf16 MFMA GEMM (B^T input, async staging, split output) ----
__global__ __launch_bounds__(256) void mfma_gemm_bt_kernel(
    const unsigned short* __restrict__ A, const unsigned short* __restrict__ WT,
    const float* __restrict__ bias, const float* __restrict__ bias2,
    unsigned short* __restrict__ C, unsigned short* __restrict__ C2,
    int M, int K, int Nout) {
    __shared__ unsigned short As[128 * 32];
    __shared__ unsigned short Bs[128 * 32];
    int tid = threadIdx.x;
    int lane = tid & 63, wid = tid >> 6;
    int gm0 = blockIdx.y * 128, gn0 = blockIdx.x * 128;
    int wm = (wid & 1) * 64, wn = (wid >> 1) * 64;
    int l15 = lane & 15, quad = lane >> 4;
    int r0 = wid * 32;
    int gr = r0 + (lane >> 2);
    int kc = (lane & 3) * 8;

    floatx4 acc[4][4];
#pragma unroll
    for (int i = 0; i < 4; i++)
#pragma unroll
        for (int j = 0; j < 4; j++)
#pragma unroll
            for (int r = 0; r < 4; r++) acc[i][j][r] = 0.f;

    const unsigned short* Ap0 = &A[(size_t)(gm0 + gr) * K + kc];
    const unsigned short* Ap1 = Ap0 + (size_t)16 * K;
    const unsigned short* Bp0 = &WT[(size_t)(gn0 + gr) * K + kc];
    const unsigned short* Bp1 = Bp0 + (size_t)16 * K;
    unsigned short* as0 = &As[r0 * 32];
    unsigned short* as1 = &As[(r0 + 16) * 32];
    unsigned short* bs0 = &Bs[r0 * 32];
    unsigned short* bs1 = &Bs[(r0 + 16) * 32];

    for (int k0 = 0; k0 < K; k0 += 32) {
        __syncthreads();
        gll16(Ap0 + k0, as0);
        gll16(Ap1 + k0, as1);
        gll16(Bp0 + k0, bs0);
        gll16(Bp1 + k0, bs1);
        __syncthreads();
        short8 af[4], bfr[4];
#pragma unroll
        for (int i = 0; i < 4; i++)
            af[i] = *(const short8*)&As[(wm + 16 * i + l15) * 32 + quad * 8];
#pragma unroll
        for (int j = 0; j < 4; j++)
            bfr[j] = *(const short8*)&Bs[(wn + 16 * j + l15) * 32 + quad * 8];
#pragma unroll
        for (int i = 0; i < 4; i++)
#pragma unroll
            for (int j = 0; j < 4; j++)
                acc[i][j] = __builtin_amdgcn_mfma_f32_16x16x32_bf16(af[i], bfr[j], acc[i][j], 0, 0, 0);
    }

    unsigned short* Cw = C;
    const float* bp = bias;
    int colb = gn0 + wn + l15;
    if (gn0 >= Nout) { Cw = C2; bp = bias2; colb -= Nout; }
#pragma unroll
    for (int i = 0; i < 4; i++) {
#pragma unroll
        for (int j = 0; j < 4; j++) {
            int col = colb + 16 * j;
            float bv = bp[col];
#pragma unroll
            for (int r = 0; r < 4; r++) {
                int rrow = gm0 + wm + 16 * i + quad * 4 + r;
                Cw[(size_t)rrow * Nout + col] = f2bits(acc[i][j][r] + bv);
            }
        }
    }
}

// ---------------- CSR build ----------------
__global__ void hist_kernel(const int* __restrict__ ei, int* __restrict__ counts, int E) {
    int e = blockIdx.x * blockDim.x + threadIdx.x;
    if (e < E) atomicAdd(&counts[ei[E + e]], 1);
}

// parallel 3-phase exclusive scan of counts[N] (N = 195*256)
__global__ __launch_bounds__(256) void block_sum_kernel(
    const int* __restrict__ counts, int* __restrict__ bsum) {
    int t = threadIdx.x;
    int v = counts[blockIdx.x * 256 + t];
#pragma unroll
    for (int off = 32; off > 0; off >>= 1) v += __shfl_xor(v, off, 64);
    __shared__ int red[4];
    if ((t & 63) == 0) red[t >> 6] = v;
    __syncthreads();
    if (t == 0) bsum[blockIdx.x] = red[0] + red[1] + red[2] + red[3];
}

__global__ __launch_bounds__(256) void bsum_scan_kernel(
    const int* __restrict__ bsum, int* __restrict__ bofs,
    int* __restrict__ offsets, int NBL, int N) {
    __shared__ int tmp[256];
    int t = threadIdx.x;
    int v = (t < NBL) ? bsum[t] : 0;
    tmp[t] = v;
    __syncthreads();
    for (int off = 1; off < 256; off <<= 1) {
        int x = (t >= off) ? tmp[t - off] : 0;
        __syncthreads();
        tmp[t] += x;
        __syncthreads();
    }
    if (t < NBL) bofs[t] = tmp[t] - v;          // exclusive
    if (t == 255) offsets[N] = tmp[255];        // total = E
}

__global__ __launch_bounds__(256) void local_scan_kernel(
    const int* __restrict__ counts, const int* __restrict__ bofs,
    int* __restrict__ offsets, int* __restrict__ woff) {
    __shared__ int tmp[256];
    int t = threadIdx.x;
    int i = blockIdx.x * 256 + t;
    int v = counts[i];
    tmp[t] = v;
    __syncthreads();
    for (int off = 1; off < 256; off <<= 1) {
        int x = (t >= off) ? tmp[t - off] : 0;
        __syncthreads();
        tmp[t] += x;
        __syncthreads();
    }
    int excl = tmp[t] - v + bofs[blockIdx.x];
    offsets[i] = excl;
    woff[i] = excl;
}

__global__ void scatter_kernel(const int* __restrict__ ei, int* __restrict__ woff,
                               int* __restrict__ perm, int* __restrict__ srcs,
                               int E) {
    int e = blockIdx.x * blockDim.x + threadIdx.x;
    if (e < E) {
        int d = ei[E + e];
        int slot = atomicAdd(&woff[d], 1);
        perm[slot] = e;
        srcs[slot] = ei[e];
    }
}

// ---------------- fused GATv2 layer: score + online-softmax + aggregate ----
// Block = 4 consecutive dst nodes; edges in 16-slot CSR chunks; ef via MFMA
// (v14/v16-verified tile, column-split for HC=1024). Heads are channel-
// local, so each xl[src] slice is loaded ONCE for both logit and acc.
// xr is the block's OWN node -> one load per (node,head) per chunk-pass.
// Online softmax: m running max (exact), s telescopes to sum exp(lg-m_fin),
// out = acc/(s+1e-16) + bias, relu. deg=0 -> acc=0,s=0 -> bias only.
// HC=1024: half-wave k=w*2+hf owns node k&3, heads {k>>2, 2+(k>>2)} (one
// per column pass); writes h1 over xr1's buffer: each half writes exactly
// the (row, head-cols) it alone reads, after its last read -> race-free.
// HC=256: wave owns node; 64 lanes cover 256 ch (4/lane), head = lane>>4.
template<int HC>
__global__ __launch_bounds__(256) void fused_gat_kernel(
    const unsigned short* __restrict__ xl, const unsigned short* __restrict__ xr,
    int XS, const float* __restrict__ eattr, const unsigned short* __restrict__ WeT,
    const float* __restrict__ att, const int* __restrict__ perm,
    const int* __restrict__ srcs, const int* __restrict__ offsets,
    const float* __restrict__ bias, void* __restrict__ outv) {
    constexpr int CW = (HC == 1024) ? 512 : 256;   // ef column window per pass
    constexpr int NP = HC / CW;                    // passes (2 or 1)
    constexpr int AW = (HC == 1024) ? 4 : 2;       // acc float2v words
    constexpr int LDE = CW + 8;
    __shared__ unsigned short ef_s[16 * LDE];
    __shared__ int src_s[16], e_s[16], off_s[5];

    int tid = threadIdx.x;
    int lane = tid & 63, w = tid >> 6;
    int l15 = lane & 15, quad = lane >> 4;
    int hf = lane >> 5, q = lane & 31;
    int n0 = blockIdx.x * 4;

    if (tid < 5) off_s[tid] = offsets[n0 + tid];
    __syncthreads();
    int s0 = off_s[0];
    int nE = off_s[4] - s0;

    // task mapping
    int node, hA = 0, c0_2 = 0;
    if constexpr (HC == 1024) {
        int k = w * 2 + hf;
        node = k & 3;
        hA = k >> 2;                       // head in pass p = hA + 2*p
    } else {
        node = w;
        c0_2 = lane * 4;                   // 4 ch/lane, head = lane>>4
    }
    int nd = n0 + node;
    int on0 = off_s[node] - s0;
    int on1 = off_s[node + 1] - s0;

    // online-softmax state (static indexing via unrolled pass loop)
    float m_[NP], s_[NP];
    float2v ac[NP][AW];
#pragma unroll
    for (int p = 0; p < NP; p++) {
        m_[p] = -3.0e38f; s_[p] = 0.f;
#pragma unroll
        for (int j = 0; j < AW; j++) ac[p][j] = (float2v){0.f, 0.f};
    }

    // HC=256 per-node preloads (pass count = 1)
    float2v r2v0 = {0.f, 0.f}, r2v1 = {0.f, 0.f}, at2v0 = {0.f, 0.f}, at2v1 = {0.f, 0.f};
    if constexpr (HC == 256) {
        uint2 wxr = *(const uint2*)&xr[(size_t)nd * XS + c0_2];
        r2v0 = cvt2(wxr.x); r2v1 = cvt2(wxr.y);
        at2v0 = (float2v){att[c0_2], att[c0_2 + 1]};
        at2v1 = (float2v){att[c0_2 + 2], att[c0_2 + 3]};
    }

    for (int cs = 0; cs < nE; cs += 16) {
        if (tid < 16) {
            int sl = cs + tid;
            int g = s0 + ((sl < nE) ? sl : 0);   // clamp: rows >= nE never consumed
            src_s[tid] = srcs[g];
            e_s[tid] = perm[g];
        }
        __syncthreads();

        // A-frag: 16 chunk edges' eattr rows (K zero-padded 16->32)
        u8x16 a;
        if (quad < 2) {
            const float* ap = &eattr[(size_t)e_s[l15] * 16 + quad * 8];
            float4 a0 = *(const float4*)ap;
            float4 a1 = *(const float4*)(ap + 4);
            a.u[0] = f2bits_trunc(a0.x); a.u[1] = f2bits_trunc(a0.y);
            a.u[2] = f2bits_trunc(a0.z); a.u[3] = f2bits_trunc(a0.w);
            a.u[4] = f2bits_trunc(a1.x); a.u[5] = f2bits_trunc(a1.y);
            a.u[6] = f2bits_trunc(a1.z); a.u[7] = f2bits_trunc(a1.w);
        } else {
#pragma unroll
            for (int j = 0; j < 8; j++) a.u[j] = 0;
        }

#pragma unroll
        for (int p = 0; p < NP; p++) {
            // phase 1: ef[:, p*CW .. +CW) for this chunk's 16 edges
            for (int t = w; t < CW / 16; t += 4) {
                int colg = p * CW + t * 16 + l15;
                u8x16 b;
                if (quad < 2) *(uint4*)b.u = *(const uint4*)&WeT[(size_t)colg * 16 + quad * 8];
                else {
#pragma unroll
                    for (int j = 0; j < 8; j++) b.u[j] = 0;
                }
                floatx4 c = {0.f, 0.f, 0.f, 0.f};
                c = __builtin_amdgcn_mfma_f32_16x16x32_bf16(a.v, b.v, c, 0, 0, 0);
#pragma unroll
                for (int r = 0; r < 4; r++)
                    ef_s[(quad * 4 + r) * LDE + t * 16 + l15] = f2bits_trunc(c[r]);
            }
            __syncthreads();

            // phase 2: score + aggregate my node's edges in this chunk
            int lo = on0 > cs ? on0 : cs;
            int hi = on1 < cs + 16 ? on1 : cs + 16;
            if constexpr (HC == 1024) {
                int head = hA + 2 * p;
                int c0g = head * 256 + q * 8;      // global col in xl/xr/att
                int c0l = hA * 256 + q * 8;        // local col in ef_s
                float2v av0 = {att[c0g], att[c0g + 1]};
                float2v av1 = {att[c0g + 2], att[c0g + 3]};
                float2v av2 = {att[c0g + 4], att[c0g + 5]};
                float2v av3 = {att[c0g + 6], att[c0g + 7]};
                uint4 wxr = *(const uint4*)&xr[(size_t)nd * XS + c0g];
                float2v r0 = cvt2(wxr.x), r1 = cvt2(wxr.y);
                float2v r2 = cvt2(wxr.z), r3 = cvt2(wxr.w);
                for (int rr = lo; rr < hi; rr++) {
                    int r = rr - cs;
                    uint4 wx = *(const uint4*)&xl[(size_t)src_s[r] * XS + c0g];
                    uint4 wf = *(const uint4*)&ef_s[r * LDE + c0l];
                    float2v x0 = cvt2(wx.x), x1 = cvt2(wx.y);
                    float2v x2 = cvt2(wx.z), x3 = cvt2(wx.w);
                    float2v v, p2 = {0.f, 0.f};
                    v = x0 + r0 + cvt2(wf.x); p2 += av0 * lrelu2(v);
                    v = x1 + r1 + cvt2(wf.y); p2 += av1 * lrelu2(v);
                    v = x2 + r2 + cvt2(wf.z); p2 += av2 * lrelu2(v);
                    v = x3 + r3 + cvt2(wf.w); p2 += av3 * lrelu2(v);
                    float lg = p2.x + p2.y;
                    lg += __shfl_xor(lg, 1, 64);
                    lg += __shfl_xor(lg, 2, 64);
                    lg += __shfl_xor(lg, 4, 64);
                    lg += __shfl_xor(lg, 8, 64);
                    lg += __shfl_xor(lg, 16, 64);
                    float mo = m_[p];
                    float mn = fmaxf(mo, lg);
                    float sc = __expf(mo - mn);
                    float tt = __expf(lg - mn);
                    m_[p] = mn;
                    s_[p] = s_[p] * sc + tt;
                    ac[p][0] = ac[p][0] * sc + x0 * tt;
                    ac[p][1] = ac[p][1] * sc + x1 * tt;
                    ac[p][2] = ac[p][2] * sc + x2 * tt;
                    ac[p][3] = ac[p][3] * sc + x3 * tt;
                }
            } else {
                for (int rr = lo; rr < hi; rr++) {
                    int r = rr - cs;
                    uint2 wx = *(const uint2*)&xl[(size_t)src_s[r] * XS + c0_2];
                    uint2 wf = *(const uint2*)&ef_s[r * LDE + c0_2];
                    float2v x0 = cvt2(wx.x), x1 = cvt2(wx.y);
                    float2v v, p2;
                    v = x0 + r2v0 + cvt2(wf.x); p2 = at2v0 * lrelu2(v);
                    v = x1 + r2v1 + cvt2(wf.y); p2 += at2v1 * lrelu2(v);
                    float lg = p2.x + p2.y;
                    lg += __shfl_xor(lg, 1, 64);
                    lg += __shfl_xor(lg, 2, 64);
                    lg += __shfl_xor(lg, 4, 64);
                    lg += __shfl_xor(lg, 8, 64);
                    float mo = m_[0];
                    float mn = fmaxf(mo, lg);
                    float sc = __expf(mo - mn);
                    float tt = __expf(lg - mn);
                    m_[0] = mn;
                    s_[0] = s_[0] * sc + tt;
                    ac[0][0] = ac[0][0] * sc + x0 * tt;
                    ac[0][1] = ac[0][1] * sc + x1 * tt;
                }
            }
            __syncthreads();   // ef_s / src_s reuse fence
        }
    }

    // finalize: out = relu(acc/(s+1e-16) + bias)
    if constexpr (HC == 1024) {
        unsigned short* o = (unsigned short*)outv;
#pragma unroll
        for (int p = 0; p < NP; p++) {
            int head = hA + 2 * p;
            int c0g = head * 256 + q * 8;
            float inv = 1.f / (s_[p] + 1e-16f);
            u8x16 wo;
#pragma unroll
            for (int j = 0; j < 4; j++) {
                float2v ov = ac[p][j] * inv + (float2v){bias[c0g + 2 * j], bias[c0g + 2 * j + 1]};
                wo.u[2 * j]     = f2bits(fmaxf(ov.x, 0.f));
                wo.u[2 * j + 1] = f2bits(fmaxf(ov.y, 0.f));
            }
            *(short8*)&o[(size_t)nd * HC + c0g] = wo.v;
        }
    } else {
        float* o = (float*)outv;
        float inv = 1.f / (s_[0] + 1e-16f);
        float4 f;
        f.x = fmaxf(ac[0][0].x * inv + bias[c0_2], 0.f);
        f.y = fmaxf(ac[0][0].y * inv + bias[c0_2 + 1], 0.f);
        f.z = fmaxf(ac[0][1].x * inv + bias[c0_2 + 2], 0.f);
        f.w = fmaxf(ac[0][1].y * inv + bias[c0_2 + 3], 0.f);
        *(float4*)&o[(size_t)nd * 256 + c0_2] = f;
    }
}

// ---------------- MLP head ----------------
__global__ __launch_bounds__(64) void mlp_head_kernel(
    const float* __restrict__ h2, const int* __restrict__ nnod,
    const float* __restrict__ w1, const float* __restrict__ b1,
    const float* __restrict__ w2, const float* __restrict__ b2,
    float* __restrict__ out, int B) {
    int b = blockIdx.x, tid = threadIdx.x;
    int sum = 0;
    for (int j = tid; j <= b; j += 64) sum += nnod[j];
#pragma unroll
    for (int off = 32; off > 0; off >>= 1) sum += __shfl_xor(sum, off, 64);
    int node = sum - 1;
    __shared__ float mast[256];
    for (int i = tid; i < 256; i += 64) mast[i] = h2[(size_t)node * 256 + i];
    __syncthreads();
    float z = 0.f;
    for (int k = 0; k < 256; k++) z += mast[k] * w1[k * 64 + tid];
    z += b1[tid];
    z = z > 0.f ? z : 0.f;
    float p = z * w2[tid];
#pragma unroll
    for (int off = 32; off > 0; off >>= 1) p += __shfl_down(p, off, 64);
    if (tid == 0) out[b] = p + b2[0];
}

extern "C" void kernel_launch(void* const* d_in, const int* in_sizes, int n_in,
                              void* d_out, int out_size, void* d_ws, size_t ws_size,
                              hipStream_t stream) {
    const float* x     = (const float*)d_in[0];
    const int*   ei    = (const int*)d_in[1];
    const float* eattr = (const float*)d_in[2];
    const int*   nnod  = (const int*)d_in[3];
    const float* Wl1 = (const float*)d_in[4];
    const float* bl1 = (const float*)d_in[5];
    const float* Wr1 = (const float*)d_in[6];
    const float* br1 = (const float*)d_in[7];
    const float* We1 = (const float*)d_in[8];
    const float* att1= (const float*)d_in[9];
    const float* b1  = (const float*)d_in[10];
    const float* Wl2 = (const float*)d_in[11];
    const float* bl2 = (const float*)d_in[12];
    const float* Wr2 = (const float*)d_in[13];
    const float* br2 = (const float*)d_in[14];
    const float* We2 = (const float*)d_in[15];
    const float* att2= (const float*)d_in[16];
    const float* b2  = (const float*)d_in[17];
    const float* fc1w= (const float*)d_in[18];
    const float* fc1b= (const float*)d_in[19];
    const float* fc2w= (const float*)d_in[20];
    const float* fc2b= (const float*)d_in[21];
    float* out = (float*)d_out;

    const int N = NN, E = EE, B = BB;
    const int NBL = N / 256;            // 195 scan blocks

    // ---------- workspace layout (unchanged from v16 baseline) ----------
    char* base = (char*)d_ws;
    const size_t NB1 = (size_t)N * 1024 * 2;
    unsigned short* xl1   = (unsigned short*)base;
    unsigned short* xlxr2 = (unsigned short*)base;                       // [N][512]
    float*          h2    = (float*)(base + (size_t)N * 512 * 2);        // [N][256] f32
    unsigned short* xr1 = (unsigned short*)(base + NB1);
    unsigned short* h1  = (unsigned short*)(base + NB1);                 // aliases xr1 (safe: see fused kernel)
    char* t = base + 2 * NB1;
    float* logits = (float*)t;        t += (size_t)E * 4 * sizeof(float);   // dead (kept for layout stability)
    int* counts   = (int*)t;          t += (size_t)N * sizeof(int);
    int* offsets  = (int*)t;          t += (size_t)(N + 1) * sizeof(int);
    int* woff     = (int*)t;          t += (size_t)N * sizeof(int);
    int* perm     = (int*)t;          t += (size_t)E * sizeof(int);
    int* srcs     = (int*)t;          t += (size_t)E * sizeof(int);
    int* dsts     = (int*)t;          t += (size_t)E * sizeof(int);         // dead
    int* bsum     = (int*)t;          t += (size_t)256 * sizeof(int);
    int* bofs     = (int*)t;          t += (size_t)256 * sizeof(int);
    t = (char*)(((uintptr_t)t + 63) & ~(uintptr_t)63);
    unsigned short* xb    = (unsigned short*)t; t += (size_t)N * 128 * 2;
    unsigned short* wtl1  = (unsigned short*)t; t += (size_t)1024 * 128 * 2;   // contiguous with
    unsigned short* wtr1  = (unsigned short*)t; t += (size_t)1024 * 128 * 2;   //  wtl1 -> [2048][128]
    unsigned short* wtlr2 = (unsigned short*)t; t += (size_t)512 * 1024 * 2;
    unsigned short* weT1  = (unsigned short*)t; t += (size_t)1024 * 16 * 2;
    unsigned short* weT2  = (unsigned short*)t; t += (size_t)256 * 16 * 2;
    float* blr2           = (float*)t;          t += (size_t)512 * sizeof(float);
    size_t required = (size_t)(t - base);
    if (ws_size < required) return;   // guard: absmax-fail instead of abort
    (void)logits; (void)dsts;

    dim3 blk(256);

    // ---------- CSR build (parallel 3-phase scan) ----------
    zero_int_kernel<<<(N + 255) / 256, blk, 0, stream>>>(counts, N);
    hist_kernel<<<(E + 255) / 256, blk, 0, stream>>>(ei, counts, E);
    block_sum_kernel<<<NBL, blk, 0, stream>>>(counts, bsum);
    bsum_scan_kernel<<<1, blk, 0, stream>>>(bsum, bofs, offsets, NBL, N);
    local_scan_kernel<<<NBL, blk, 0, stream>>>(counts, bofs, offsets, woff);
    scatter_kernel<<<(E + 255) / 256, blk, 0, stream>>>(ei, woff, perm, srcs, E);

    // ---------- conversions ----------
    convert_bf16_kernel<<<(N * 128 + 255) / 256, blk, 0, stream>>>(x, xb, N * 128);
    convert_weights_kernel<<<3154, blk, 0, stream>>>(Wl1, Wr1, Wl2, Wr2, We1, We2, bl2, br2,
                                                     wtl1, wtr1, wtlr2, weT1, weT2, blr2);

    // ---------- layer 1 (fused xl|xr GEMM, then fused score+agg) ----------
    {
        dim3 g1(2048 / 128, N / 128);
        mfma_gemm_bt_kernel<<<g1, blk, 0, stream>>>(xb, wtl1, bl1, br1, xl1, xr1, N, 128, 1024);
    }
    fused_gat_kernel<1024><<<N / 4, blk, 0, stream>>>(xl1, xr1, 1024, eattr, weT1, att1, perm, srcs, offsets, b1, h1);

    // ---------- layer 2 (fused xl|xr GEMM, then fused score+agg) ----------
    {
        dim3 g2(512 / 128, N / 128);
        mfma_gemm_bt_kernel<<<g2, blk, 0, stream>>>(h1, wtlr2, blr2, blr2, xlxr2, xlxr2, N, 1024, 512);
    }
    fused_gat_kernel<256><<<N / 4, blk, 0, stream>>>(xlxr2, xlxr2 + 256, 512, eattr, weT2, att2, perm, srcs, offsets, b2, h2);

    // ---------- head ----------
    mlp_head_kernel<<<B, 64, 0, stream>>>(h2, nnod, fc1w, fc1b, fc2w, fc2b, out, B);
}

// Round 8
// 558.459 us; speedup vs baseline: 1.2666x; 1.2666x over previous
//
#include <hip/hip_runtime.h>
#include <hip/hip_bf16.h>
#include <cmath>

#define NN 49920
#define EE 200000
#define BB 128

typedef __attribute__((ext_vector_type(8))) short short8;
typedef __attribute__((ext_vector_type(4))) float floatx4;
typedef __attribute__((ext_vector_type(2))) float float2v;

union u8x16 { short8 v; unsigned short u[8]; };

__device__ __forceinline__ float bits2f(unsigned short u) {
    union { unsigned int i; float f; } c; c.i = ((unsigned int)u) << 16; return c.f;
}
__device__ __forceinline__ unsigned short f2bits(float f) {
    union { float f; unsigned int i; } c; c.f = f;
    unsigned int x = c.i;
    return (unsigned short)((x + 0x7fffu + ((x >> 16) & 1u)) >> 16);   // RNE
}
__device__ __forceinline__ unsigned short f2bits_trunc(float f) {
    union { float f; unsigned int i; } c; c.f = f;
    return (unsigned short)(c.i >> 16);                               // truncate (1 op)
}
__device__ __forceinline__ float2v cvt2(unsigned int w) {
    union { unsigned int i; float f; } lo, hi;
    lo.i = w << 16; hi.i = w & 0xffff0000u;
    return (float2v){lo.f, hi.f};
}
// exact leaky_relu(v) = max(v, 0.2v)
__device__ __forceinline__ float2v lrelu2(float2v v) {
    float2v t = v * 0.2f;
    return (float2v){fmaxf(v.x, t.x), fmaxf(v.y, t.y)};
}

typedef const __attribute__((address_space(1))) void* gvp;
typedef __attribute__((address_space(3))) void* lvp;
__device__ __forceinline__ void gll16(const void* g, void* l) {
    __builtin_amdgcn_global_load_lds((gvp)g, (lvp)l, 16, 0, 0);
}

// ---------------- small utility kernels ----------------
__global__ void zero_int_kernel(int* __restrict__ p, int n) {
    int i = blockIdx.x * blockDim.x + threadIdx.x;
    if (i < n) p[i] = 0;
}

// vectorized f32 -> bf16 (float4 in, ushort4 out; n4 = n/4)
__global__ void convert_bf16_kernel(const float4* __restrict__ src, ushort4* __restrict__ dst, int n4) {
    int i = blockIdx.x * blockDim.x + threadIdx.x;
    if (i < n4) {
        float4 v = src[i];
        ushort4 o;
        o.x = f2bits(v.x); o.y = f2bits(v.y);
        o.z = f2bits(v.z); o.w = f2bits(v.w);
        dst[i] = o;
    }
}

// fused conversion of ALL weights
__global__ void convert_weights_kernel(
    const float* __restrict__ Wl1, const float* __restrict__ Wr1,
    const float* __restrict__ Wl2, const float* __restrict__ Wr2,
    const float* __restrict__ We1, const float* __restrict__ We2,
    const float* __restrict__ bl2, const float* __restrict__ br2,
    unsigned short* __restrict__ wtl1, unsigned short* __restrict__ wtr1,
    unsigned short* __restrict__ wtlr2, unsigned short* __restrict__ weT1,
    unsigned short* __restrict__ weT2, float* __restrict__ blr2) {
    int b = blockIdx.x, tid = threadIdx.x;
    if (b < 1024) {                       // Wl1/Wr1 [128][1024] -> WT [1024][128]
        const float* W = (b < 512) ? Wl1 : Wr1;
        unsigned short* WT = (b < 512) ? wtl1 : wtr1;
        int i = ((b & 511) << 8) + tid;
        int n = i >> 7, k = i & 127;
        WT[i] = f2bits(W[k * 1024 + n]);
    } else if (b < 3072) {                // Wl2/Wr2 [1024][256] -> wtlr2 [512][1024]
        int bb = b - 1024;
        const float* W = (bb < 1024) ? Wl2 : Wr2;
        int i = ((bb & 1023) << 8) + tid;
        int n = i >> 10, k = i & 1023;
        int off = (bb < 1024) ? 0 : 262144;
        wtlr2[off + i] = f2bits(W[k * 256 + n]);
    } else if (b < 3136) {                // We1 [16][1024] -> weT1 [1024][16]
        int i = ((b - 3072) << 8) + tid;
        int col = i >> 4, k = i & 15;
        weT1[i] = f2bits(We1[k * 1024 + col]);
    } else if (b < 3152) {                // We2 [16][256] -> weT2 [256][16]
        int i = ((b - 3136) << 8) + tid;
        int col = i >> 4, k = i & 15;
        weT2[i] = f2bits(We2[k * 256 + col]);
    } else {                              // blr2 = bl2 | br2 (512 f32)
        int i = ((b - 3152) << 8) + tid;
        if (i < 512) blr2[i] = (i < 256) ? bl2[i] : br2[i - 256];
    }
}

// ---------------- bf16 MFMA GEMM (B^T input, async staging, split output) ----
__global__ __launch_bounds__(256) void mfma_gemm_bt_kernel(
    const unsigned short* __restrict__ A, const unsigned short* __restrict__ WT,
    const float* __restrict__ bias, const float* __restrict__ bias2,
    unsigned short* __restrict__ C, unsigned short* __restrict__ C2,
    int M, int K, int Nout) {
    __shared__ unsigned short As[128 * 32];
    __shared__ unsigned short Bs[128 * 32];
    int tid = threadIdx.x;
    int lane = tid & 63, wid = tid >> 6;
    int gm0 = blockIdx.y * 128, gn0 = blockIdx.x * 128;
    int wm = (wid & 1) * 64, wn = (wid >> 1) * 64;
    int l15 = lane & 15, quad = lane >> 4;
    int r0 = wid * 32;
    int gr = r0 + (lane >> 2);
    int kc = (lane & 3) * 8;

    floatx4 acc[4][4];
#pragma unroll
    for (int i = 0; i < 4; i++)
#pragma unroll
        for (int j = 0; j < 4; j++)
#pragma unroll
            for (int r = 0; r < 4; r++) acc[i][j][r] = 0.f;

    const unsigned short* Ap0 = &A[(size_t)(gm0 + gr) * K + kc];
    const unsigned short* Ap1 = Ap0 + (size_t)16 * K;
    const unsigned short* Bp0 = &WT[(size_t)(gn0 + gr) * K + kc];
    const unsigned short* Bp1 = Bp0 + (size_t)16 * K;
    unsigned short* as0 = &As[r0 * 32];
    unsigned short* as1 = &As[(r0 + 16) * 32];
    unsigned short* bs0 = &Bs[r0 * 32];
    unsigned short* bs1 = &Bs[(r0 + 16) * 32];

    for (int k0 = 0; k0 < K; k0 += 32) {
        __syncthreads();
        gll16(Ap0 + k0, as0);
        gll16(Ap1 + k0, as1);
        gll16(Bp0 + k0, bs0);
        gll16(Bp1 + k0, bs1);
        __syncthreads();
        short8 af[4], bfr[4];
#pragma unroll
        for (int i = 0; i < 4; i++)
            af[i] = *(const short8*)&As[(wm + 16 * i + l15) * 32 + quad * 8];
#pragma unroll
        for (int j = 0; j < 4; j++)
            bfr[j] = *(const short8*)&Bs[(wn + 16 * j + l15) * 32 + quad * 8];
#pragma unroll
        for (int i = 0; i < 4; i++)
#pragma unroll
            for (int j = 0; j < 4; j++)
                acc[i][j] = __builtin_amdgcn_mfma_f32_16x16x32_bf16(af[i], bfr[j], acc[i][j], 0, 0, 0);
    }

    unsigned short* Cw = C;
    const float* bp = bias;
    int colb = gn0 + wn + l15;
    if (gn0 >= Nout) { Cw = C2; bp = bias2; colb -= Nout; }
#pragma unroll
    for (int i = 0; i < 4; i++) {
#pragma unroll
        for (int j = 0; j < 4; j++) {
            int col = colb + 16 * j;
            float bv = bp[col];
#pragma unroll
            for (int r = 0; r < 4; r++) {
                int rrow = gm0 + wm + 16 * i + quad * 4 + r;
                Cw[(size_t)rrow * Nout + col] = f2bits(acc[i][j][r] + bv);
            }
        }
    }
}

// ---------------- CSR build ----------------
__global__ void hist_kernel(const int* __restrict__ ei, int* __restrict__ counts, int E) {
    int e = blockIdx.x * blockDim.x + threadIdx.x;
    if (e < E) atomicAdd(&counts[ei[E + e]], 1);
}

// parallel 3-phase exclusive scan of counts[N] (N = 195*256)
__global__ __launch_bounds__(256) void block_sum_kernel(
    const int* __restrict__ counts, int* __restrict__ bsum) {
    int t = threadIdx.x;
    int v = counts[blockIdx.x * 256 + t];
#pragma unroll
    for (int off = 32; off > 0; off >>= 1) v += __shfl_xor(v, off, 64);
    __shared__ int red[4];
    if ((t & 63) == 0) red[t >> 6] = v;
    __syncthreads();
    if (t == 0) bsum[blockIdx.x] = red[0] + red[1] + red[2] + red[3];
}

__global__ __launch_bounds__(256) void bsum_scan_kernel(
    const int* __restrict__ bsum, int* __restrict__ bofs,
    int* __restrict__ offsets, int NBL, int N) {
    __shared__ int tmp[256];
    int t = threadIdx.x;
    int v = (t < NBL) ? bsum[t] : 0;
    tmp[t] = v;
    __syncthreads();
    for (int off = 1; off < 256; off <<= 1) {
        int x = (t >= off) ? tmp[t - off] : 0;
        __syncthreads();
        tmp[t] += x;
        __syncthreads();
    }
    if (t < NBL) bofs[t] = tmp[t] - v;          // exclusive
    if (t == 255) offsets[N] = tmp[255];        // total = E
}

__global__ __launch_bounds__(256) void local_scan_kernel(
    const int* __restrict__ counts, const int* __restrict__ bofs,
    int* __restrict__ offsets, int* __restrict__ woff) {
    __shared__ int tmp[256];
    int t = threadIdx.x;
    int i = blockIdx.x * 256 + t;
    int v = counts[i];
    tmp[t] = v;
    __syncthreads();
    for (int off = 1; off < 256; off <<= 1) {
        int x = (t >= off) ? tmp[t - off] : 0;
        __syncthreads();
        tmp[t] += x;
        __syncthreads();
    }
    int excl = tmp[t] - v + bofs[blockIdx.x];
    offsets[i] = excl;
    woff[i] = excl;
}

__global__ void scatter_kernel(const int* __restrict__ ei, int* __restrict__ woff,
                               int* __restrict__ perm, int* __restrict__ srcs,
                               int* __restrict__ dsts, int E) {
    int e = blockIdx.x * blockDim.x + threadIdx.x;
    if (e < E) {
        int d = ei[E + e];
        int slot = atomicAdd(&woff[d], 1);
        perm[slot] = e;
        srcs[slot] = ei[e];
        dsts[slot] = d;
    }
}

// ---------------- edge scoring v16: EB=16, column-split passes, consecutive-
// edge walk + xr dst-dedup (TA-transaction reduction) + exact max(v,0.2v).
template<int HC>
__global__ __launch_bounds__(256) void edge_score_v16_kernel(
    const unsigned short* __restrict__ xl, const unsigned short* __restrict__ xr,
    int XS, const float* __restrict__ eattr, const unsigned short* __restrict__ WeT,
    const float* __restrict__ att, const int* __restrict__ perm,
    const int* __restrict__ srcs, const int* __restrict__ dsts,
    float* __restrict__ logits, int E) {
    constexpr int EB = 16;
    constexpr int CW = (HC == 1024) ? 512 : 256;   // column window per pass
    constexpr int NP = HC / CW;                    // passes (2 or 1)
    constexpr int LDE = CW + 8;
    __shared__ unsigned short ef_s[EB * LDE];
    __shared__ int src_s[EB], dst_s[EB], e_s[16];
    __shared__ float logit_s[EB * 4];

    int tid = threadIdx.x;
    int s0 = blockIdx.x * EB;
    int lane = tid & 63, w = tid >> 6;
    int l15 = lane & 15, quad = lane >> 4;
    int hf = lane >> 5, q = lane & 31;

    if (tid < EB) { src_s[tid] = srcs[s0 + tid]; dst_s[tid] = dsts[s0 + tid]; }
    if (tid < 16) e_s[tid] = perm[s0 + tid];
    __syncthreads();

    // A-frag: eattr rows (K zero-padded 16->32); trunc conversion (global only)
    u8x16 a;
    if (quad < 2) {
        const float* ap = &eattr[(size_t)e_s[l15] * 16 + quad * 8];
        float4 a0 = *(const float4*)ap;
        float4 a1 = *(const float4*)(ap + 4);
        a.u[0] = f2bits_trunc(a0.x); a.u[1] = f2bits_trunc(a0.y);
        a.u[2] = f2bits_trunc(a0.z); a.u[3] = f2bits_trunc(a0.w);
        a.u[4] = f2bits_trunc(a1.x); a.u[5] = f2bits_trunc(a1.y);
        a.u[6] = f2bits_trunc(a1.z); a.u[7] = f2bits_trunc(a1.w);
    } else {
#pragma unroll
        for (int j = 0; j < 8; j++) a.u[j] = 0;
    }

#pragma unroll
    for (int half = 0; half < NP; half++) {
        // Phase 1: ef[:, half*CW .. +CW) = eattr @ We -> LDS (bf16 trunc)
        for (int t = w; t < CW / 16; t += 4) {
            int colg = half * CW + t * 16 + l15;
            u8x16 b;
            if (quad < 2) *(uint4*)b.u = *(const uint4*)&WeT[(size_t)colg * 16 + quad * 8];
            else {
#pragma unroll
                for (int j = 0; j < 8; j++) b.u[j] = 0;
            }
            floatx4 c = {0.f, 0.f, 0.f, 0.f};
            c = __builtin_amdgcn_mfma_f32_16x16x32_bf16(a.v, b.v, c, 0, 0, 0);
#pragma unroll
            for (int r = 0; r < 4; r++)
                ef_s[(quad * 4 + r) * LDE + t * 16 + l15] = f2bits_trunc(c[r]);
        }
        __syncthreads();

        // Phase 2: half-wave per (edge, head); lane covers 8 ch (uint4).
        if constexpr (HC == 1024) {
            int hloc = w >> 1;                 // local head in this pass (0/1)
            int head = half * 2 + hloc;        // global head
            int slot = (w & 1) * 2 + hf;       // edge group 0..3
            int c0g = head * 256 + q * 8;      // col in xl/xr/att
            int c0l = hloc * 256 + q * 8;      // col in ef_s
            float2v attv[4];
#pragma unroll
            for (int j = 0; j < 4; j++)
                attv[j] = (float2v){att[c0g + 2 * j], att[c0g + 2 * j + 1]};
            // prefetch the 4 xl gathers (independent, consecutive edges)
            uint4 wlp[4];
#pragma unroll
            for (int pp = 0; pp < 4; pp++)
                wlp[pp] = *(const uint4*)&xl[(size_t)src_s[slot * 4 + pp] * XS + c0g];
            int prevd = -1;
            float2v r0, r1, r2, r3;
            r0 = r1 = r2 = r3 = (float2v){0.f, 0.f};
#pragma unroll
            for (int pp = 0; pp < 4; pp++) {
                int e = slot * 4 + pp;         // consecutive CSR slots
                int d = dst_s[e];
                if (d != prevd) {              // uniform within 32-lane half
                    uint4 wr = *(const uint4*)&xr[(size_t)d * XS + c0g];
                    r0 = cvt2(wr.x); r1 = cvt2(wr.y); r2 = cvt2(wr.z); r3 = cvt2(wr.w);
                    prevd = d;
                }
                uint4 wf = *(const uint4*)&ef_s[e * LDE + c0l];
                float2v v, p2 = {0.f, 0.f};
                v = cvt2(wlp[pp].x) + r0 + cvt2(wf.x); p2 += attv[0] * lrelu2(v);
                v = cvt2(wlp[pp].y) + r1 + cvt2(wf.y); p2 += attv[1] * lrelu2(v);
                v = cvt2(wlp[pp].z) + r2 + cvt2(wf.z); p2 += attv[2] * lrelu2(v);
                v = cvt2(wlp[pp].w) + r3 + cvt2(wf.w); p2 += attv[3] * lrelu2(v);
                float part = p2.x + p2.y;
                part += __shfl_xor(part, 1, 64);
                part += __shfl_xor(part, 2, 64);
                part += __shfl_xor(part, 4, 64);
                part += __shfl_xor(part, 8, 64);
                part += __shfl_xor(part, 16, 64);
                if (q == 0) logit_s[e * 4 + head] = part;
            }
        } else {
            int c0 = q * 8;                       // all 256 ch over 32 lanes
            int hd = q >> 3;                      // lane's head
            float2v attv[4];
#pragma unroll
            for (int j = 0; j < 4; j++)
                attv[j] = (float2v){att[c0 + 2 * j], att[c0 + 2 * j + 1]};
            uint4 wlp[2];
#pragma unroll
            for (int pp = 0; pp < 2; pp++)
                wlp[pp] = *(const uint4*)&xl[(size_t)src_s[w * 4 + hf * 2 + pp] * XS + c0];
            int prevd = -1;
            float2v r0, r1, r2, r3;
            r0 = r1 = r2 = r3 = (float2v){0.f, 0.f};
#pragma unroll
            for (int pp = 0; pp < 2; pp++) {
                int e = w * 4 + hf * 2 + pp;      // consecutive CSR slots
                int d = dst_s[e];
                if (d != prevd) {                 // uniform within 32-lane half
                    uint4 wr = *(const uint4*)&xr[(size_t)d * XS + c0];
                    r0 = cvt2(wr.x); r1 = cvt2(wr.y); r2 = cvt2(wr.z); r3 = cvt2(wr.w);
                    prevd = d;
                }
                uint4 wf = *(const uint4*)&ef_s[e * LDE + c0];
                float2v v, p2 = {0.f, 0.f};
                v = cvt2(wlp[pp].x) + r0 + cvt2(wf.x); p2 += attv[0] * lrelu2(v);
                v = cvt2(wlp[pp].y) + r1 + cvt2(wf.y); p2 += attv[1] * lrelu2(v);
                v = cvt2(wlp[pp].z) + r2 + cvt2(wf.z); p2 += attv[2] * lrelu2(v);
                v = cvt2(wlp[pp].w) + r3 + cvt2(wf.w); p2 += attv[3] * lrelu2(v);
                float part = p2.x + p2.y;
                part += __shfl_xor(part, 1, 64);
                part += __shfl_xor(part, 2, 64);
                part += __shfl_xor(part, 4, 64);
                if ((q & 7) == 0) logit_s[e * 4 + hd] = part;
            }
        }
        __syncthreads();   // ef_s reuse fence (also logit_s fence on last pass)
    }
    if (tid < EB * 4) logits[(size_t)s0 * 4 + tid] = logit_s[tid];
}

// ---------------- node aggregation: WPN waves per node, 4-unrolled gather ----
// softmax max+sum fused: one logits read per edge (register-held) for the
// common deg<=stride case; strided fallback loops kept for correctness.
template<int HC, int WPN, bool OUT_BF16>
__global__ __launch_bounds__(256) void node_agg_wave_kernel(
    const unsigned short* __restrict__ xl, int XS, const float* __restrict__ logits,
    const int* __restrict__ srcs, const int* __restrict__ offsets,
    const float* __restrict__ bias, void* __restrict__ outv) {
    constexpr int J = HC / (64 * WPN);    // 8 (L1) or 4 (L2)
    int tid = threadIdx.x;
    int wid = tid >> 6, lane = tid & 63;
    int n, ha;
    if constexpr (WPN == 2) { n = blockIdx.x * 2 + (wid >> 1); ha = wid & 1; }
    else { n = blockIdx.x * 4 + wid; ha = 0; }
    int o0 = offsets[n];
    int deg = offsets[n + 1] - o0;

    int hl;
    float m, s;
    if constexpr (WPN == 2) {
        hl = ha * 2 + (lane >> 5);
        int p = lane & 31;
        float lv = (p < deg) ? logits[(size_t)(o0 + p) * 4 + hl] : -3.0e38f;
        m = lv;
        for (int i = p + 32; i < deg; i += 32)              // rare (deg>32)
            m = fmaxf(m, logits[(size_t)(o0 + i) * 4 + hl]);
        m = fmaxf(m, __shfl_xor(m, 1, 64));
        m = fmaxf(m, __shfl_xor(m, 2, 64));
        m = fmaxf(m, __shfl_xor(m, 4, 64));
        m = fmaxf(m, __shfl_xor(m, 8, 64));
        m = fmaxf(m, __shfl_xor(m, 16, 64));
        s = (p < deg) ? __expf(lv - m) : 0.f;
        for (int i = p + 32; i < deg; i += 32)              // rare (deg>32)
            s += __expf(logits[(size_t)(o0 + i) * 4 + hl] - m);
        s += __shfl_xor(s, 1, 64);
        s += __shfl_xor(s, 2, 64);
        s += __shfl_xor(s, 4, 64);
        s += __shfl_xor(s, 8, 64);
        s += __shfl_xor(s, 16, 64);
    } else {
        hl = lane >> 4;
        int p = lane & 15;
        float lv = (p < deg) ? logits[(size_t)(o0 + p) * 4 + hl] : -3.0e38f;
        m = lv;
        for (int i = p + 16; i < deg; i += 16)              // rare (deg>16)
            m = fmaxf(m, logits[(size_t)(o0 + i) * 4 + hl]);
        m = fmaxf(m, __shfl_xor(m, 1, 64));
        m = fmaxf(m, __shfl_xor(m, 2, 64));
        m = fmaxf(m, __shfl_xor(m, 4, 64));
        m = fmaxf(m, __shfl_xor(m, 8, 64));
        s = (p < deg) ? __expf(lv - m) : 0.f;
        for (int i = p + 16; i < deg; i += 16)              // rare (deg>16)
            s += __expf(logits[(size_t)(o0 + i) * 4 + hl] - m);
        s += __shfl_xor(s, 1, 64);
        s += __shfl_xor(s, 2, 64);
        s += __shfl_xor(s, 4, 64);
        s += __shfl_xor(s, 8, 64);
    }
    float inv = 1.f / (s + 1e-16f);

    int c0 = ha * (HC / WPN) + lane * J;
    float acc[J];
#pragma unroll
    for (int v = 0; v < J; v++) acc[v] = bias[c0 + v];

    int i = 0;
    // 4-wide: all gathers issued before exp/fma consumption
    for (; i + 4 <= deg; i += 4) {
        int sl0 = o0 + i, sl1 = o0 + i + 1, sl2 = o0 + i + 2, sl3 = o0 + i + 3;
        int src0 = srcs[sl0], src1 = srcs[sl1], src2 = srcs[sl2], src3 = srcs[sl3];
        if constexpr (J == 8) {
            u8x16 a0, a1, a2, a3;
            a0.v = *(const short8*)&xl[(size_t)src0 * XS + c0];
            a1.v = *(const short8*)&xl[(size_t)src1 * XS + c0];
            a2.v = *(const short8*)&xl[(size_t)src2 * XS + c0];
            a3.v = *(const short8*)&xl[(size_t)src3 * XS + c0];
            float alpha0 = __expf(logits[(size_t)sl0 * 4 + hl] - m) * inv;
            float alpha1 = __expf(logits[(size_t)sl1 * 4 + hl] - m) * inv;
            float alpha2 = __expf(logits[(size_t)sl2 * 4 + hl] - m) * inv;
            float alpha3 = __expf(logits[(size_t)sl3 * 4 + hl] - m) * inv;
#pragma unroll
            for (int v = 0; v < 8; v++) {
                acc[v] += alpha0 * bits2f(a0.u[v]) + alpha1 * bits2f(a1.u[v]);
                acc[v] += alpha2 * bits2f(a2.u[v]) + alpha3 * bits2f(a3.u[v]);
            }
        } else {
            unsigned short u0[4], u1[4], u2[4], u3[4];
            *(ushort4*)u0 = *(const ushort4*)&xl[(size_t)src0 * XS + c0];
            *(ushort4*)u1 = *(const ushort4*)&xl[(size_t)src1 * XS + c0];
            *(ushort4*)u2 = *(const ushort4*)&xl[(size_t)src2 * XS + c0];
            *(ushort4*)u3 = *(const ushort4*)&xl[(size_t)src3 * XS + c0];
            float alpha0 = __expf(logits[(size_t)sl0 * 4 + hl] - m) * inv;
            float alpha1 = __expf(logits[(size_t)sl1 * 4 + hl] - m) * inv;
            float alpha2 = __expf(logits[(size_t)sl2 * 4 + hl] - m) * inv;
            float alpha3 = __expf(logits[(size_t)sl3 * 4 + hl] - m) * inv;
#pragma unroll
            for (int v = 0; v < 4; v++) {
                acc[v] += alpha0 * bits2f(u0[v]) + alpha1 * bits2f(u1[v]);
                acc[v] += alpha2 * bits2f(u2[v]) + alpha3 * bits2f(u3[v]);
            }
        }
    }
    for (; i + 2 <= deg; i += 2) {
        int sl0 = o0 + i, sl1 = o0 + i + 1;
        int src0 = srcs[sl0], src1 = srcs[sl1];
        const unsigned short* row0 = &xl[(size_t)src0 * XS + c0];
        const unsigned short* row1 = &xl[(size_t)src1 * XS + c0];
        float alpha0 = __expf(logits[(size_t)sl0 * 4 + hl] - m) * inv;
        float alpha1 = __expf(logits[(size_t)sl1 * 4 + hl] - m) * inv;
        if constexpr (J == 8) {
            u8x16 a0, a1;
            a0.v = *(const short8*)row0;
            a1.v = *(const short8*)row1;
#pragma unroll
            for (int v = 0; v < 8; v++) acc[v] += alpha0 * bits2f(a0.u[v]) + alpha1 * bits2f(a1.u[v]);
        } else {
            unsigned short u0[4], u1[4];
            *(ushort4*)u0 = *(const ushort4*)row0;
            *(ushort4*)u1 = *(const ushort4*)row1;
#pragma unroll
            for (int v = 0; v < 4; v++) acc[v] += alpha0 * bits2f(u0[v]) + alpha1 * bits2f(u1[v]);
        }
    }
    if (i < deg) {
        int sl = o0 + i;
        float alpha = __expf(logits[(size_t)sl * 4 + hl] - m) * inv;
        int src = srcs[sl];
        const unsigned short* row = &xl[(size_t)src * XS + c0];
        if constexpr (J == 8) {
            u8x16 a0; a0.v = *(const short8*)row;
#pragma unroll
            for (int v = 0; v < 8; v++) acc[v] += alpha * bits2f(a0.u[v]);
        } else {
            unsigned short us[4];
            *(ushort4*)us = *(const ushort4*)row;
#pragma unroll
            for (int v = 0; v < 4; v++) acc[v] += alpha * bits2f(us[v]);
        }
    }

    if constexpr (OUT_BF16) {
        unsigned short* o = (unsigned short*)outv;
        u8x16 w0;
#pragma unroll
        for (int v = 0; v < 8; v++) w0.u[v] = f2bits(fmaxf(acc[v], 0.f));
        *(short8*)&o[(size_t)n * HC + c0] = w0.v;
    } else {
        float* o = (float*)outv;
        float4 f;
        f.x = fmaxf(acc[0], 0.f); f.y = fmaxf(acc[1], 0.f);
        f.z = fmaxf(acc[2], 0.f); f.w = fmaxf(acc[3], 0.f);
        *(float4*)&o[(size_t)n * HC + c0] = f;
    }
}

// ---------------- MLP head ----------------
__global__ __launch_bounds__(64) void mlp_head_kernel(
    const float* __restrict__ h2, const int* __restrict__ nnod,
    const float* __restrict__ w1, const float* __restrict__ b1,
    const float* __restrict__ w2, const float* __restrict__ b2,
    float* __restrict__ out, int B) {
    int b = blockIdx.x, tid = threadIdx.x;
    int sum = 0;
    for (int j = tid; j <= b; j += 64) sum += nnod[j];
#pragma unroll
    for (int off = 32; off > 0; off >>= 1) sum += __shfl_xor(sum, off, 64);
    int node = sum - 1;
    __shared__ float mast[256];
    for (int i = tid; i < 256; i += 64) mast[i] = h2[(size_t)node * 256 + i];
    __syncthreads();
    float z = 0.f;
    for (int k = 0; k < 256; k++) z += mast[k] * w1[k * 64 + tid];
    z += b1[tid];
    z = z > 0.f ? z : 0.f;
    float p = z * w2[tid];
#pragma unroll
    for (int off = 32; off > 0; off >>= 1) p += __shfl_down(p, off, 64);
    if (tid == 0) out[b] = p + b2[0];
}

extern "C" void kernel_launch(void* const* d_in, const int* in_sizes, int n_in,
                              void* d_out, int out_size, void* d_ws, size_t ws_size,
                              hipStream_t stream) {
    const float* x     = (const float*)d_in[0];
    const int*   ei    = (const int*)d_in[1];
    const float* eattr = (const float*)d_in[2];
    const int*   nnod  = (const int*)d_in[3];
    const float* Wl1 = (const float*)d_in[4];
    const float* bl1 = (const float*)d_in[5];
    const float* Wr1 = (const float*)d_in[6];
    const float* br1 = (const float*)d_in[7];
    const float* We1 = (const float*)d_in[8];
    const float* att1= (const float*)d_in[9];
    const float* b1  = (const float*)d_in[10];
    const float* Wl2 = (const float*)d_in[11];
    const float* bl2 = (const float*)d_in[12];
    const float* Wr2 = (const float*)d_in[13];
    const float* br2 = (const float*)d_in[14];
    const float* We2 = (const float*)d_in[15];
    const float* att2= (const float*)d_in[16];
    const float* b2  = (const float*)d_in[17];
    const float* fc1w= (const float*)d_in[18];
    const float* fc1b= (const float*)d_in[19];
    const float* fc2w= (const float*)d_in[20];
    const float* fc2b= (const float*)d_in[21];
    float* out = (float*)d_out;

    const int N = NN, E = EE, B = BB;
    const int NBL = N / 256;            // 195 scan blocks

    // ---------- workspace layout ----------
    char* base = (char*)d_ws;
    const size_t NB1 = (size_t)N * 1024 * 2;
    unsigned short* xl1   = (unsigned short*)base;
    unsigned short* xlxr2 = (unsigned short*)base;                       // [N][512]
    float*          h2    = (float*)(base + (size_t)N * 512 * 2);        // [N][256] f32
    unsigned short* xr1 = (unsigned short*)(base + NB1);
    unsigned short* h1  = (unsigned short*)(base + NB1);
    char* t = base + 2 * NB1;
    float* logits = (float*)t;        t += (size_t)E * 4 * sizeof(float);
    int* counts   = (int*)t;          t += (size_t)N * sizeof(int);
    int* offsets  = (int*)t;          t += (size_t)(N + 1) * sizeof(int);
    int* woff     = (int*)t;          t += (size_t)N * sizeof(int);
    int* perm     = (int*)t;          t += (size_t)E * sizeof(int);
    int* srcs     = (int*)t;          t += (size_t)E * sizeof(int);
    int* dsts     = (int*)t;          t += (size_t)E * sizeof(int);
    int* bsum     = (int*)t;          t += (size_t)256 * sizeof(int);
    int* bofs     = (int*)t;          t += (size_t)256 * sizeof(int);
    t = (char*)(((uintptr_t)t + 63) & ~(uintptr_t)63);
    unsigned short* xb    = (unsigned short*)t; t += (size_t)N * 128 * 2;
    unsigned short* wtl1  = (unsigned short*)t; t += (size_t)1024 * 128 * 2;   // contiguous with
    unsigned short* wtr1  = (unsigned short*)t; t += (size_t)1024 * 128 * 2;   //  wtl1 -> [2048][128]
    unsigned short* wtlr2 = (unsigned short*)t; t += (size_t)512 * 1024 * 2;
    unsigned short* weT1  = (unsigned short*)t; t += (size_t)1024 * 16 * 2;
    unsigned short* weT2  = (unsigned short*)t; t += (size_t)256 * 16 * 2;
    float* blr2           = (float*)t;          t += (size_t)512 * sizeof(float);
    size_t required = (size_t)(t - base);
    if (ws_size < required) return;   // guard: absmax-fail instead of abort

    dim3 blk(256);

    // ---------- CSR build (parallel 3-phase scan) ----------
    zero_int_kernel<<<(N + 255) / 256, blk, 0, stream>>>(counts, N);
    hist_kernel<<<(E + 255) / 256, blk, 0, stream>>>(ei, counts, E);
    block_sum_kernel<<<NBL, blk, 0, stream>>>(counts, bsum);
    bsum_scan_kernel<<<1, blk, 0, stream>>>(bsum, bofs, offsets, NBL, N);
    local_scan_kernel<<<NBL, blk, 0, stream>>>(counts, bofs, offsets, woff);
    scatter_kernel<<<(E + 255) / 256, blk, 0, stream>>>(ei, woff, perm, srcs, dsts, E);

    // ---------- conversions ----------
    convert_bf16_kernel<<<(N * 32 + 255) / 256, blk, 0, stream>>>((const float4*)x, (ushort4*)xb, N * 32);
    convert_weights_kernel<<<3154, blk, 0, stream>>>(Wl1, Wr1, Wl2, Wr2, We1, We2, bl2, br2,
                                                     wtl1, wtr1, wtlr2, weT1, weT2, blr2);

    // ---------- layer 1 (fused xl|xr GEMM, Ntot=2048, split write) ----------
    {
        dim3 g1(2048 / 128, N / 128);
        mfma_gemm_bt_kernel<<<g1, blk, 0, stream>>>(xb, wtl1, bl1, br1, xl1, xr1, N, 128, 1024);
    }
    edge_score_v16_kernel<1024><<<E / 16, blk, 0, stream>>>(xl1, xr1, 1024, eattr, weT1, att1, perm, srcs, dsts, logits, E);
    node_agg_wave_kernel<1024, 2, true><<<N / 2, blk, 0, stream>>>(xl1, 1024, logits, srcs, offsets, b1, h1);

    // ---------- layer 2 (fused xl|xr GEMM, N=512) ----------
    {
        dim3 g2(512 / 128, N / 128);
        mfma_gemm_bt_kernel<<<g2, blk, 0, stream>>>(h1, wtlr2, blr2, blr2, xlxr2, xlxr2, N, 1024, 512);
    }
    edge_score_v16_kernel<256><<<E / 16, blk, 0, stream>>>(xlxr2, xlxr2 + 256, 512, eattr, weT2, att2, perm, srcs, dsts, logits, E);
    node_agg_wave_kernel<256, 1, false><<<N / 4, blk, 0, stream>>>(xlxr2, 512, logits, srcs, offsets, b2, h2);

    // ---------- head ----------
    mlp_head_kernel<<<B, 64, 0, stream>>>(h2, nnod, fc1w, fc1b, fc2w, fc2b, out, B);
}

// Round 9
// 548.729 us; speedup vs baseline: 1.2890x; 1.0177x over previous
//
#include <hip/hip_runtime.h>
#include <hip/hip_bf16.h>
#include <cmath>

#define NN 49920
#define EE 200000
#define BB 128

typedef __attribute__((ext_vector_type(8))) short short8;
typedef __attribute__((ext_vector_type(4))) float floatx4;
typedef __attribute__((ext_vector_type(2))) float float2v;

union u8x16 { short8 v; unsigned short u[8]; };

__device__ __forceinline__ float bits2f(unsigned short u) {
    union { unsigned int i; float f; } c; c.i = ((unsigned int)u) << 16; return c.f;
}
__device__ __forceinline__ unsigned short f2bits(float f) {
    union { float f; unsigned int i; } c; c.f = f;
    unsigned int x = c.i;
    return (unsigned short)((x + 0x7fffu + ((x >> 16) & 1u)) >> 16);   // RNE
}
__device__ __forceinline__ unsigned short f2bits_trunc(float f) {
    union { float f; unsigned int i; } c; c.f = f;
    return (unsigned short)(c.i >> 16);                               // truncate (1 op)
}
__device__ __forceinline__ float2v cvt2(unsigned int w) {
    union { unsigned int i; float f; } lo, hi;
    lo.i = w << 16; hi.i = w & 0xffff0000u;
    return (float2v){lo.f, hi.f};
}
// exact leaky_relu(v) = max(v, 0.2v)
__device__ __forceinline__ float2v lrelu2(float2v v) {
    float2v t = v * 0.2f;
    return (float2v){fmaxf(v.x, t.x), fmaxf(v.y, t.y)};
}

typedef const __attribute__((address_space(1))) void* gvp;
typedef __attribute__((address_space(3))) void* lvp;
__device__ __forceinline__ void gll16(const void* g, void* l) {
    __builtin_amdgcn_global_load_lds((gvp)g, (lvp)l, 16, 0, 0);
}

// ---------------- small utility kernels ----------------
__global__ void zero_int_kernel(int* __restrict__ p, int n) {
    int i = blockIdx.x * blockDim.x + threadIdx.x;
    if (i < n) p[i] = 0;
}

// vectorized f32 -> bf16 (float4 in, ushort4 out; n4 = n/4)
__global__ void convert_bf16_kernel(const float4* __restrict__ src, ushort4* __restrict__ dst, int n4) {
    int i = blockIdx.x * blockDim.x + threadIdx.x;
    if (i < n4) {
        float4 v = src[i];
        ushort4 o;
        o.x = f2bits(v.x); o.y = f2bits(v.y);
        o.z = f2bits(v.z); o.w = f2bits(v.w);
        dst[i] = o;
    }
}

// fused conversion of ALL weights
__global__ void convert_weights_kernel(
    const float* __restrict__ Wl1, const float* __restrict__ Wr1,
    const float* __restrict__ Wl2, const float* __restrict__ Wr2,
    const float* __restrict__ We1, const float* __restrict__ We2,
    const float* __restrict__ bl2, const float* __restrict__ br2,
    unsigned short* __restrict__ wtl1, unsigned short* __restrict__ wtr1,
    unsigned short* __restrict__ wtlr2, unsigned short* __restrict__ weT1,
    unsigned short* __restrict__ weT2, float* __restrict__ blr2) {
    int b = blockIdx.x, tid = threadIdx.x;
    if (b < 1024) {                       // Wl1/Wr1 [128][1024] -> WT [1024][128]
        const float* W = (b < 512) ? Wl1 : Wr1;
        unsigned short* WT = (b < 512) ? wtl1 : wtr1;
        int i = ((b & 511) << 8) + tid;
        int n = i >> 7, k = i & 127;
        WT[i] = f2bits(W[k * 1024 + n]);
    } else if (b < 3072) {                // Wl2/Wr2 [1024][256] -> wtlr2 [512][1024]
        int bb = b - 1024;
        const float* W = (bb < 1024) ? Wl2 : Wr2;
        int i = ((bb & 1023) << 8) + tid;
        int n = i >> 10, k = i & 1023;
        int off = (bb < 1024) ? 0 : 262144;
        wtlr2[off + i] = f2bits(W[k * 256 + n]);
    } else if (b < 3136) {                // We1 [16][1024] -> weT1 [1024][16]
        int i = ((b - 3072) << 8) + tid;
        int col = i >> 4, k = i & 15;
        weT1[i] = f2bits(We1[k * 1024 + col]);
    } else if (b < 3152) {                // We2 [16][256] -> weT2 [256][16]
        int i = ((b - 3136) << 8) + tid;
        int col = i >> 4, k = i & 15;
        weT2[i] = f2bits(We2[k * 256 + col]);
    } else {                              // blr2 = bl2 | br2 (512 f32)
        int i = ((b - 3152) << 8) + tid;
        if (i < 512) blr2[i] = (i < 256) ? bl2[i] : br2[i - 256];
    }
}

// ---------------- bf16 MFMA GEMM (B^T input, async staging, split output) ----
__global__ __launch_bounds__(256) void mfma_gemm_bt_kernel(
    const unsigned short* __restrict__ A, const unsigned short* __restrict__ WT,
    const float* __restrict__ bias, const float* __restrict__ bias2,
    unsigned short* __restrict__ C, unsigned short* __restrict__ C2,
    int M, int K, int Nout) {
    __shared__ unsigned short As[128 * 32];
    __shared__ unsigned short Bs[128 * 32];
    int tid = threadIdx.x;
    int lane = tid & 63, wid = tid >> 6;
    int gm0 = blockIdx.y * 128, gn0 = blockIdx.x * 128;
    int wm = (wid & 1) * 64, wn = (wid >> 1) * 64;
    int l15 = lane & 15, quad = lane >> 4;
    int r0 = wid * 32;
    int gr = r0 + (lane >> 2);
    int kc = (lane & 3) * 8;

    floatx4 acc[4][4];
#pragma unroll
    for (int i = 0; i < 4; i++)
#pragma unroll
        for (int j = 0; j < 4; j++)
#pragma unroll
            for (int r = 0; r < 4; r++) acc[i][j][r] = 0.f;

    const unsigned short* Ap0 = &A[(size_t)(gm0 + gr) * K + kc];
    const unsigned short* Ap1 = Ap0 + (size_t)16 * K;
    const unsigned short* Bp0 = &WT[(size_t)(gn0 + gr) * K + kc];
    const unsigned short* Bp1 = Bp0 + (size_t)16 * K;
    unsigned short* as0 = &As[r0 * 32];
    unsigned short* as1 = &As[(r0 + 16) * 32];
    unsigned short* bs0 = &Bs[r0 * 32];
    unsigned short* bs1 = &Bs[(r0 + 16) * 32];

    for (int k0 = 0; k0 < K; k0 += 32) {
        __syncthreads();
        gll16(Ap0 + k0, as0);
        gll16(Ap1 + k0, as1);
        gll16(Bp0 + k0, bs0);
        gll16(Bp1 + k0, bs1);
        __syncthreads();
        short8 af[4], bfr[4];
#pragma unroll
        for (int i = 0; i < 4; i++)
            af[i] = *(const short8*)&As[(wm + 16 * i + l15) * 32 + quad * 8];
#pragma unroll
        for (int j = 0; j < 4; j++)
            bfr[j] = *(const short8*)&Bs[(wn + 16 * j + l15) * 32 + quad * 8];
#pragma unroll
        for (int i = 0; i < 4; i++)
#pragma unroll
            for (int j = 0; j < 4; j++)
                acc[i][j] = __builtin_amdgcn_mfma_f32_16x16x32_bf16(af[i], bfr[j], acc[i][j], 0, 0, 0);
    }

    unsigned short* Cw = C;
    const float* bp = bias;
    int colb = gn0 + wn + l15;
    if (gn0 >= Nout) { Cw = C2; bp = bias2; colb -= Nout; }
#pragma unroll
    for (int i = 0; i < 4; i++) {
#pragma unroll
        for (int j = 0; j < 4; j++) {
            int col = colb + 16 * j;
            float bv = bp[col];
#pragma unroll
            for (int r = 0; r < 4; r++) {
                int rrow = gm0 + wm + 16 * i + quad * 4 + r;
                Cw[(size_t)rrow * Nout + col] = f2bits(acc[i][j][r] + bv);
            }
        }
    }
}

// ---------------- CSR build ----------------
__global__ void hist_kernel(const int* __restrict__ ei, int* __restrict__ counts, int E) {
    int e = blockIdx.x * blockDim.x + threadIdx.x;
    if (e < E) atomicAdd(&counts[ei[E + e]], 1);
}

// parallel 3-phase exclusive scan of counts[N] (N = 195*256)
__global__ __launch_bounds__(256) void block_sum_kernel(
    const int* __restrict__ counts, int* __restrict__ bsum) {
    int t = threadIdx.x;
    int v = counts[blockIdx.x * 256 + t];
#pragma unroll
    for (int off = 32; off > 0; off >>= 1) v += __shfl_xor(v, off, 64);
    __shared__ int red[4];
    if ((t & 63) == 0) red[t >> 6] = v;
    __syncthreads();
    if (t == 0) bsum[blockIdx.x] = red[0] + red[1] + red[2] + red[3];
}

__global__ __launch_bounds__(256) void bsum_scan_kernel(
    const int* __restrict__ bsum, int* __restrict__ bofs,
    int* __restrict__ offsets, int NBL, int N) {
    __shared__ int tmp[256];
    int t = threadIdx.x;
    int v = (t < NBL) ? bsum[t] : 0;
    tmp[t] = v;
    __syncthreads();
    for (int off = 1; off < 256; off <<= 1) {
        int x = (t >= off) ? tmp[t - off] : 0;
        __syncthreads();
        tmp[t] += x;
        __syncthreads();
    }
    if (t < NBL) bofs[t] = tmp[t] - v;          // exclusive
    if (t == 255) offsets[N] = tmp[255];        // total = E
}

__global__ __launch_bounds__(256) void local_scan_kernel(
    const int* __restrict__ counts, const int* __restrict__ bofs,
    int* __restrict__ offsets, int* __restrict__ woff) {
    __shared__ int tmp[256];
    int t = threadIdx.x;
    int i = blockIdx.x * 256 + t;
    int v = counts[i];
    tmp[t] = v;
    __syncthreads();
    for (int off = 1; off < 256; off <<= 1) {
        int x = (t >= off) ? tmp[t - off] : 0;
        __syncthreads();
        tmp[t] += x;
        __syncthreads();
    }
    int excl = tmp[t] - v + bofs[blockIdx.x];
    offsets[i] = excl;
    woff[i] = excl;
}

__global__ void scatter_kernel(const int* __restrict__ ei, int* __restrict__ woff,
                               int* __restrict__ perm, int* __restrict__ srcs,
                               int* __restrict__ dsts, int E) {
    int e = blockIdx.x * blockDim.x + threadIdx.x;
    if (e < E) {
        int d = ei[E + e];
        int slot = atomicAdd(&woff[d], 1);
        perm[slot] = e;
        srcs[slot] = ei[e];
        dsts[slot] = d;
    }
}

// ---------------- edge scoring v17 ----------------
// HC=1024: EB=16, two 512-col passes (unchanged from v16).
// HC=256:  EB=32 (NEW): two A-frags share each WeT B-load (2 MFMA/t-iter),
//          half the blocks, same 16.9KB LDS; dedup runs of 4.
template<int HC>
__global__ __launch_bounds__(256) void edge_score_v17_kernel(
    const unsigned short* __restrict__ xl, const unsigned short* __restrict__ xr,
    int XS, const float* __restrict__ eattr, const unsigned short* __restrict__ WeT,
    const float* __restrict__ att, const int* __restrict__ perm,
    const int* __restrict__ srcs, const int* __restrict__ dsts,
    float* __restrict__ logits, int E) {
    constexpr int EB = (HC == 1024) ? 16 : 32;
    constexpr int CW = (HC == 1024) ? 512 : 256;   // column window per pass
    constexpr int NP = HC / CW;                    // passes (2 or 1)
    constexpr int LDE = CW + 8;
    __shared__ unsigned short ef_s[EB * LDE];
    __shared__ int src_s[EB], dst_s[EB], e_s[EB];
    __shared__ float logit_s[EB * 4];

    int tid = threadIdx.x;
    int s0 = blockIdx.x * EB;
    int lane = tid & 63, w = tid >> 6;
    int l15 = lane & 15, quad = lane >> 4;
    int hf = lane >> 5, q = lane & 31;

    if (tid < EB) { src_s[tid] = srcs[s0 + tid]; dst_s[tid] = dsts[s0 + tid]; e_s[tid] = perm[s0 + tid]; }
    __syncthreads();

    // A-frag(s): eattr rows (K zero-padded 16->32); trunc conversion
    u8x16 a0f;
    if (quad < 2) {
        const float* ap = &eattr[(size_t)e_s[l15] * 16 + quad * 8];
        float4 a0 = *(const float4*)ap;
        float4 a1 = *(const float4*)(ap + 4);
        a0f.u[0] = f2bits_trunc(a0.x); a0f.u[1] = f2bits_trunc(a0.y);
        a0f.u[2] = f2bits_trunc(a0.z); a0f.u[3] = f2bits_trunc(a0.w);
        a0f.u[4] = f2bits_trunc(a1.x); a0f.u[5] = f2bits_trunc(a1.y);
        a0f.u[6] = f2bits_trunc(a1.z); a0f.u[7] = f2bits_trunc(a1.w);
    } else {
#pragma unroll
        for (int j = 0; j < 8; j++) a0f.u[j] = 0;
    }
    u8x16 a1f;                          // second 16 edges (EB=32 only)
    if constexpr (EB == 32) {
        if (quad < 2) {
            const float* ap = &eattr[(size_t)e_s[16 + l15] * 16 + quad * 8];
            float4 a0 = *(const float4*)ap;
            float4 a1 = *(const float4*)(ap + 4);
            a1f.u[0] = f2bits_trunc(a0.x); a1f.u[1] = f2bits_trunc(a0.y);
            a1f.u[2] = f2bits_trunc(a0.z); a1f.u[3] = f2bits_trunc(a0.w);
            a1f.u[4] = f2bits_trunc(a1.x); a1f.u[5] = f2bits_trunc(a1.y);
            a1f.u[6] = f2bits_trunc(a1.z); a1f.u[7] = f2bits_trunc(a1.w);
        } else {
#pragma unroll
            for (int j = 0; j < 8; j++) a1f.u[j] = 0;
        }
    }

#pragma unroll
    for (int half = 0; half < NP; half++) {
        // Phase 1: ef[:, half*CW .. +CW) = eattr @ We -> LDS (bf16 trunc)
        for (int t = w; t < CW / 16; t += 4) {
            int colg = half * CW + t * 16 + l15;
            u8x16 b;
            if (quad < 2) *(uint4*)b.u = *(const uint4*)&WeT[(size_t)colg * 16 + quad * 8];
            else {
#pragma unroll
                for (int j = 0; j < 8; j++) b.u[j] = 0;
            }
            floatx4 c = {0.f, 0.f, 0.f, 0.f};
            c = __builtin_amdgcn_mfma_f32_16x16x32_bf16(a0f.v, b.v, c, 0, 0, 0);
#pragma unroll
            for (int r = 0; r < 4; r++)
                ef_s[(quad * 4 + r) * LDE + t * 16 + l15] = f2bits_trunc(c[r]);
            if constexpr (EB == 32) {
                floatx4 c2 = {0.f, 0.f, 0.f, 0.f};
                c2 = __builtin_amdgcn_mfma_f32_16x16x32_bf16(a1f.v, b.v, c2, 0, 0, 0);
#pragma unroll
                for (int r = 0; r < 4; r++)
                    ef_s[(16 + quad * 4 + r) * LDE + t * 16 + l15] = f2bits_trunc(c2[r]);
            }
        }
        __syncthreads();

        // Phase 2: half-wave per (edge, head); lane covers 8 ch (uint4).
        if constexpr (HC == 1024) {
            int hloc = w >> 1;                 // local head in this pass (0/1)
            int head = half * 2 + hloc;        // global head
            int slot = (w & 1) * 2 + hf;       // edge group 0..3
            int c0g = head * 256 + q * 8;      // col in xl/xr/att
            int c0l = hloc * 256 + q * 8;      // col in ef_s
            float2v attv[4];
#pragma unroll
            for (int j = 0; j < 4; j++)
                attv[j] = (float2v){att[c0g + 2 * j], att[c0g + 2 * j + 1]};
            // prefetch the 4 xl gathers (independent, consecutive edges)
            uint4 wlp[4];
#pragma unroll
            for (int pp = 0; pp < 4; pp++)
                wlp[pp] = *(const uint4*)&xl[(size_t)src_s[slot * 4 + pp] * XS + c0g];
            int prevd = -1;
            float2v r0, r1, r2, r3;
            r0 = r1 = r2 = r3 = (float2v){0.f, 0.f};
#pragma unroll
            for (int pp = 0; pp < 4; pp++) {
                int e = slot * 4 + pp;         // consecutive CSR slots
                int d = dst_s[e];
                if (d != prevd) {              // uniform within 32-lane half
                    uint4 wr = *(const uint4*)&xr[(size_t)d * XS + c0g];
                    r0 = cvt2(wr.x); r1 = cvt2(wr.y); r2 = cvt2(wr.z); r3 = cvt2(wr.w);
                    prevd = d;
                }
                uint4 wf = *(const uint4*)&ef_s[e * LDE + c0l];
                float2v v, p2 = {0.f, 0.f};
                v = cvt2(wlp[pp].x) + r0 + cvt2(wf.x); p2 += attv[0] * lrelu2(v);
                v = cvt2(wlp[pp].y) + r1 + cvt2(wf.y); p2 += attv[1] * lrelu2(v);
                v = cvt2(wlp[pp].z) + r2 + cvt2(wf.z); p2 += attv[2] * lrelu2(v);
                v = cvt2(wlp[pp].w) + r3 + cvt2(wf.w); p2 += attv[3] * lrelu2(v);
                float part = p2.x + p2.y;
                part += __shfl_xor(part, 1, 64);
                part += __shfl_xor(part, 2, 64);
                part += __shfl_xor(part, 4, 64);
                part += __shfl_xor(part, 8, 64);
                part += __shfl_xor(part, 16, 64);
                if (q == 0) logit_s[e * 4 + head] = part;
            }
        } else {
            int c0 = q * 8;                       // all 256 ch over 32 lanes
            int hd = q >> 3;                      // lane's head
            float2v attv[4];
#pragma unroll
            for (int j = 0; j < 4; j++)
                attv[j] = (float2v){att[c0 + 2 * j], att[c0 + 2 * j + 1]};
            uint4 wlp[4];
#pragma unroll
            for (int pp = 0; pp < 4; pp++)
                wlp[pp] = *(const uint4*)&xl[(size_t)src_s[w * 8 + hf * 4 + pp] * XS + c0];
            int prevd = -1;
            float2v r0, r1, r2, r3;
            r0 = r1 = r2 = r3 = (float2v){0.f, 0.f};
#pragma unroll
            for (int pp = 0; pp < 4; pp++) {
                int e = w * 8 + hf * 4 + pp;      // consecutive CSR slots
                int d = dst_s[e];
                if (d != prevd) {                 // uniform within 32-lane half
                    uint4 wr = *(const uint4*)&xr[(size_t)d * XS + c0];
                    r0 = cvt2(wr.x); r1 = cvt2(wr.y); r2 = cvt2(wr.z); r3 = cvt2(wr.w);
                    prevd = d;
                }
                uint4 wf = *(const uint4*)&ef_s[e * LDE + c0];
                float2v v, p2 = {0.f, 0.f};
                v = cvt2(wlp[pp].x) + r0 + cvt2(wf.x); p2 += attv[0] * lrelu2(v);
                v = cvt2(wlp[pp].y) + r1 + cvt2(wf.y); p2 += attv[1] * lrelu2(v);
                v = cvt2(wlp[pp].z) + r2 + cvt2(wf.z); p2 += attv[2] * lrelu2(v);
                v = cvt2(wlp[pp].w) + r3 + cvt2(wf.w); p2 += attv[3] * lrelu2(v);
                float part = p2.x + p2.y;
                part += __shfl_xor(part, 1, 64);
                part += __shfl_xor(part, 2, 64);
                part += __shfl_xor(part, 4, 64);
                if ((q & 7) == 0) logit_s[e * 4 + hd] = part;
            }
        }
        __syncthreads();   // ef_s reuse fence (also logit_s fence on last pass)
    }
    if (tid < EB * 4) logits[(size_t)s0 * 4 + tid] = logit_s[tid];
}

// ---------------- node aggregation: WPN waves per node, 4-unrolled gather ----
template<int HC, int WPN, bool OUT_BF16>
__global__ __launch_bounds__(256) void node_agg_wave_kernel(
    const unsigned short* __restrict__ xl, int XS, const float* __restrict__ logits,
    const int* __restrict__ srcs, const int* __restrict__ offsets,
    const float* __restrict__ bias, void* __restrict__ outv) {
    constexpr int J = HC / (64 * WPN);    // 8 (L1) or 4 (L2)
    int tid = threadIdx.x;
    int wid = tid >> 6, lane = tid & 63;
    int n, ha;
    if constexpr (WPN == 2) { n = blockIdx.x * 2 + (wid >> 1); ha = wid & 1; }
    else { n = blockIdx.x * 4 + wid; ha = 0; }
    int o0 = offsets[n];
    int deg = offsets[n + 1] - o0;

    int hl;
    float m, s;
    if constexpr (WPN == 2) {
        hl = ha * 2 + (lane >> 5);
        int p = lane & 31;
        float lv = (p < deg) ? logits[(size_t)(o0 + p) * 4 + hl] : -3.0e38f;
        m = lv;
        for (int i = p + 32; i < deg; i += 32)              // rare (deg>32)
            m = fmaxf(m, logits[(size_t)(o0 + i) * 4 + hl]);
        m = fmaxf(m, __shfl_xor(m, 1, 64));
        m = fmaxf(m, __shfl_xor(m, 2, 64));
        m = fmaxf(m, __shfl_xor(m, 4, 64));
        m = fmaxf(m, __shfl_xor(m, 8, 64));
        m = fmaxf(m, __shfl_xor(m, 16, 64));
        s = (p < deg) ? __expf(lv - m) : 0.f;
        for (int i = p + 32; i < deg; i += 32)              // rare (deg>32)
            s += __expf(logits[(size_t)(o0 + i) * 4 + hl] - m);
        s += __shfl_xor(s, 1, 64);
        s += __shfl_xor(s, 2, 64);
        s += __shfl_xor(s, 4, 64);
        s += __shfl_xor(s, 8, 64);
        s += __shfl_xor(s, 16, 64);
    } else {
        hl = lane >> 4;
        int p = lane & 15;
        float lv = (p < deg) ? logits[(size_t)(o0 + p) * 4 + hl] : -3.0e38f;
        m = lv;
        for (int i = p + 16; i < deg; i += 16)              // rare (deg>16)
            m = fmaxf(m, logits[(size_t)(o0 + i) * 4 + hl]);
        m = fmaxf(m, __shfl_xor(m, 1, 64));
        m = fmaxf(m, __shfl_xor(m, 2, 64));
        m = fmaxf(m, __shfl_xor(m, 4, 64));
        m = fmaxf(m, __shfl_xor(m, 8, 64));
        s = (p < deg) ? __expf(lv - m) : 0.f;
        for (int i = p + 16; i < deg; i += 16)              // rare (deg>16)
            s += __expf(logits[(size_t)(o0 + i) * 4 + hl] - m);
        s += __shfl_xor(s, 1, 64);
        s += __shfl_xor(s, 2, 64);
        s += __shfl_xor(s, 4, 64);
        s += __shfl_xor(s, 8, 64);
    }
    float inv = 1.f / (s + 1e-16f);

    int c0 = ha * (HC / WPN) + lane * J;
    float acc[J];
#pragma unroll
    for (int v = 0; v < J; v++) acc[v] = bias[c0 + v];

    int i = 0;
    // 4-wide: all gathers issued before exp/fma consumption
    for (; i + 4 <= deg; i += 4) {
        int sl0 = o0 + i, sl1 = o0 + i + 1, sl2 = o0 + i + 2, sl3 = o0 + i + 3;
        int src0 = srcs[sl0], src1 = srcs[sl1], src2 = srcs[sl2], src3 = srcs[sl3];
        if constexpr (J == 8) {
            u8x16 a0, a1, a2, a3;
            a0.v = *(const short8*)&xl[(size_t)src0 * XS + c0];
            a1.v = *(const short8*)&xl[(size_t)src1 * XS + c0];
            a2.v = *(const short8*)&xl[(size_t)src2 * XS + c0];
            a3.v = *(const short8*)&xl[(size_t)src3 * XS + c0];
            float alpha0 = __expf(logits[(size_t)sl0 * 4 + hl] - m) * inv;
            float alpha1 = __expf(logits[(size_t)sl1 * 4 + hl] - m) * inv;
            float alpha2 = __expf(logits[(size_t)sl2 * 4 + hl] - m) * inv;
            float alpha3 = __expf(logits[(size_t)sl3 * 4 + hl] - m) * inv;
#pragma unroll
            for (int v = 0; v < 8; v++) {
                acc[v] += alpha0 * bits2f(a0.u[v]) + alpha1 * bits2f(a1.u[v]);
                acc[v] += alpha2 * bits2f(a2.u[v]) + alpha3 * bits2f(a3.u[v]);
            }
        } else {
            unsigned short u0[4], u1[4], u2[4], u3[4];
            *(ushort4*)u0 = *(const ushort4*)&xl[(size_t)src0 * XS + c0];
            *(ushort4*)u1 = *(const ushort4*)&xl[(size_t)src1 * XS + c0];
            *(ushort4*)u2 = *(const ushort4*)&xl[(size_t)src2 * XS + c0];
            *(ushort4*)u3 = *(const ushort4*)&xl[(size_t)src3 * XS + c0];
            float alpha0 = __expf(logits[(size_t)sl0 * 4 + hl] - m) * inv;
            float alpha1 = __expf(logits[(size_t)sl1 * 4 + hl] - m) * inv;
            float alpha2 = __expf(logits[(size_t)sl2 * 4 + hl] - m) * inv;
            float alpha3 = __expf(logits[(size_t)sl3 * 4 + hl] - m) * inv;
#pragma unroll
            for (int v = 0; v < 4; v++) {
                acc[v] += alpha0 * bits2f(u0[v]) + alpha1 * bits2f(u1[v]);
                acc[v] += alpha2 * bits2f(u2[v]) + alpha3 * bits2f(u3[v]);
            }
        }
    }
    for (; i + 2 <= deg; i += 2) {
        int sl0 = o0 + i, sl1 = o0 + i + 1;
        int src0 = srcs[sl0], src1 = srcs[sl1];
        const unsigned short* row0 = &xl[(size_t)src0 * XS + c0];
        const unsigned short* row1 = &xl[(size_t)src1 * XS + c0];
        float alpha0 = __expf(logits[(size_t)sl0 * 4 + hl] - m) * inv;
        float alpha1 = __expf(logits[(size_t)sl1 * 4 + hl] - m) * inv;
        if constexpr (J == 8) {
            u8x16 a0, a1;
            a0.v = *(const short8*)row0;
            a1.v = *(const short8*)row1;
#pragma unroll
            for (int v = 0; v < 8; v++) acc[v] += alpha0 * bits2f(a0.u[v]) + alpha1 * bits2f(a1.u[v]);
        } else {
            unsigned short u0[4], u1[4];
            *(ushort4*)u0 = *(const ushort4*)row0;
            *(ushort4*)u1 = *(const ushort4*)row1;
#pragma unroll
            for (int v = 0; v < 4; v++) acc[v] += alpha0 * bits2f(u0[v]) + alpha1 * bits2f(u1[v]);
        }
    }
    if (i < deg) {
        int sl = o0 + i;
        float alpha = __expf(logits[(size_t)sl * 4 + hl] - m) * inv;
        int src = srcs[sl];
        const unsigned short* row = &xl[(size_t)src * XS + c0];
        if constexpr (J == 8) {
            u8x16 a0; a0.v = *(const short8*)row;
#pragma unroll
            for (int v = 0; v < 8; v++) acc[v] += alpha * bits2f(a0.u[v]);
        } else {
            unsigned short us[4];
            *(ushort4*)us = *(const ushort4*)row;
#pragma unroll
            for (int v = 0; v < 4; v++) acc[v] += alpha * bits2f(us[v]);
        }
    }

    if constexpr (OUT_BF16) {
        unsigned short* o = (unsigned short*)outv;
        u8x16 w0;
#pragma unroll
        for (int v = 0; v < 8; v++) w0.u[v] = f2bits(fmaxf(acc[v], 0.f));
        *(short8*)&o[(size_t)n * HC + c0] = w0.v;
    } else {
        float* o = (float*)outv;
        float4 f;
        f.x = fmaxf(acc[0], 0.f); f.y = fmaxf(acc[1], 0.f);
        f.z = fmaxf(acc[2], 0.f); f.w = fmaxf(acc[3], 0.f);
        *(float4*)&o[(size_t)n * HC + c0] = f;
    }
}

// ---------------- MLP head ----------------
__global__ __launch_bounds__(64) void mlp_head_kernel(
    const float* __restrict__ h2, const int* __restrict__ nnod,
    const float* __restrict__ w1, const float* __restrict__ b1,
    const float* __restrict__ w2, const float* __restrict__ b2,
    float* __restrict__ out, int B) {
    int b = blockIdx.x, tid = threadIdx.x;
    int sum = 0;
    for (int j = tid; j <= b; j += 64) sum += nnod[j];
#pragma unroll
    for (int off = 32; off > 0; off >>= 1) sum += __shfl_xor(sum, off, 64);
    int node = sum - 1;
    __shared__ float mast[256];
    for (int i = tid; i < 256; i += 64) mast[i] = h2[(size_t)node * 256 + i];
    __syncthreads();
    float z = 0.f;
    for (int k = 0; k < 256; k++) z += mast[k] * w1[k * 64 + tid];
    z += b1[tid];
    z = z > 0.f ? z : 0.f;
    float p = z * w2[tid];
#pragma unroll
    for (int off = 32; off > 0; off >>= 1) p += __shfl_down(p, off, 64);
    if (tid == 0) out[b] = p + b2[0];
}

extern "C" void kernel_launch(void* const* d_in, const int* in_sizes, int n_in,
                              void* d_out, int out_size, void* d_ws, size_t ws_size,
                              hipStream_t stream) {
    const float* x     = (const float*)d_in[0];
    const int*   ei    = (const int*)d_in[1];
    const float* eattr = (const float*)d_in[2];
    const int*   nnod  = (const int*)d_in[3];
    const float* Wl1 = (const float*)d_in[4];
    const float* bl1 = (const float*)d_in[5];
    const float* Wr1 = (const float*)d_in[6];
    const float* br1 = (const float*)d_in[7];
    const float* We1 = (const float*)d_in[8];
    const float* att1= (const float*)d_in[9];
    const float* b1  = (const float*)d_in[10];
    const float* Wl2 = (const float*)d_in[11];
    const float* bl2 = (const float*)d_in[12];
    const float* Wr2 = (const float*)d_in[13];
    const float* br2 = (const float*)d_in[14];
    const float* We2 = (const float*)d_in[15];
    const float* att2= (const float*)d_in[16];
    const float* b2  = (const float*)d_in[17];
    const float* fc1w= (const float*)d_in[18];
    const float* fc1b= (const float*)d_in[19];
    const float* fc2w= (const float*)d_in[20];
    const float* fc2b= (const float*)d_in[21];
    float* out = (float*)d_out;

    const int N = NN, E = EE, B = BB;
    const int NBL = N / 256;            // 195 scan blocks

    // ---------- workspace layout ----------
    char* base = (char*)d_ws;
    const size_t NB1 = (size_t)N * 1024 * 2;
    unsigned short* xl1   = (unsigned short*)base;
    unsigned short* xlxr2 = (unsigned short*)base;                       // [N][512]
    float*          h2    = (float*)(base + (size_t)N * 512 * 2);        // [N][256] f32
    unsigned short* xr1 = (unsigned short*)(base + NB1);
    unsigned short* h1  = (unsigned short*)(base + NB1);
    char* t = base + 2 * NB1;
    float* logits = (float*)t;        t += (size_t)E * 4 * sizeof(float);
    int* counts   = (int*)t;          t += (size_t)N * sizeof(int);
    int* offsets  = (int*)t;          t += (size_t)(N + 1) * sizeof(int);
    int* woff     = (int*)t;          t += (size_t)N * sizeof(int);
    int* perm     = (int*)t;          t += (size_t)E * sizeof(int);
    int* srcs     = (int*)t;          t += (size_t)E * sizeof(int);
    int* dsts     = (int*)t;          t += (size_t)E * sizeof(int);
    int* bsum     = (int*)t;          t += (size_t)256 * sizeof(int);
    int* bofs     = (int*)t;          t += (size_t)256 * sizeof(int);
    t = (char*)(((uintptr_t)t + 63) & ~(uintptr_t)63);
    unsigned short* xb    = (unsigned short*)t; t += (size_t)N * 128 * 2;
    unsigned short* wtl1  = (unsigned short*)t; t += (size_t)1024 * 128 * 2;   // contiguous with
    unsigned short* wtr1  = (unsigned short*)t; t += (size_t)1024 * 128 * 2;   //  wtl1 -> [2048][128]
    unsigned short* wtlr2 = (unsigned short*)t; t += (size_t)512 * 1024 * 2;
    unsigned short* weT1  = (unsigned short*)t; t += (size_t)1024 * 16 * 2;
    unsigned short* weT2  = (unsigned short*)t; t += (size_t)256 * 16 * 2;
    float* blr2           = (float*)t;          t += (size_t)512 * sizeof(float);
    size_t required = (size_t)(t - base);
    if (ws_size < required) return;   // guard: absmax-fail instead of abort

    dim3 blk(256);

    // ---------- CSR build (parallel 3-phase scan) ----------
    zero_int_kernel<<<(N + 255) / 256, blk, 0, stream>>>(counts, N);
    hist_kernel<<<(E + 255) / 256, blk, 0, stream>>>(ei, counts, E);
    block_sum_kernel<<<NBL, blk, 0, stream>>>(counts, bsum);
    bsum_scan_kernel<<<1, blk, 0, stream>>>(bsum, bofs, offsets, NBL, N);
    local_scan_kernel<<<NBL, blk, 0, stream>>>(counts, bofs, offsets, woff);
    scatter_kernel<<<(E + 255) / 256, blk, 0, stream>>>(ei, woff, perm, srcs, dsts, E);

    // ---------- conversions ----------
    convert_bf16_kernel<<<(N * 32 + 255) / 256, blk, 0, stream>>>((const float4*)x, (ushort4*)xb, N * 32);
    convert_weights_kernel<<<3154, blk, 0, stream>>>(Wl1, Wr1, Wl2, Wr2, We1, We2, bl2, br2,
                                                     wtl1, wtr1, wtlr2, weT1, weT2, blr2);

    // ---------- layer 1 (fused xl|xr GEMM, Ntot=2048, split write) ----------
    {
        dim3 g1(2048 / 128, N / 128);
        mfma_gemm_bt_kernel<<<g1, blk, 0, stream>>>(xb, wtl1, bl1, br1, xl1, xr1, N, 128, 1024);
    }
    edge_score_v17_kernel<1024><<<E / 16, blk, 0, stream>>>(xl1, xr1, 1024, eattr, weT1, att1, perm, srcs, dsts, logits, E);
    node_agg_wave_kernel<1024, 2, true><<<N / 2, blk, 0, stream>>>(xl1, 1024, logits, srcs, offsets, b1, h1);

    // ---------- layer 2 (fused xl|xr GEMM, N=512) ----------
    {
        dim3 g2(512 / 128, N / 128);
        mfma_gemm_bt_kernel<<<g2, blk, 0, stream>>>(h1, wtlr2, blr2, blr2, xlxr2, xlxr2, N, 1024, 512);
    }
    edge_score_v17_kernel<256><<<E / 32, blk, 0, stream>>>(xlxr2, xlxr2 + 256, 512, eattr, weT2, att2, perm, srcs, dsts, logits, E);
    node_agg_wave_kernel<256, 1, false><<<N / 4, blk, 0, stream>>>(xlxr2, 512, logits, srcs, offsets, b2, h2);

    // ---------- head ----------
    mlp_head_kernel<<<B, 64, 0, stream>>>(h2, nnod, fc1w, fc1b, fc2w, fc2b, out, B);
}

// Round 10
// 543.517 us; speedup vs baseline: 1.3014x; 1.0096x over previous
//
#include <hip/hip_runtime.h>
#include <hip/hip_bf16.h>
#include <cmath>

#define NN 49920
#define EE 200000
#define BB 128

typedef __attribute__((ext_vector_type(8))) short short8;
typedef __attribute__((ext_vector_type(4))) float floatx4;
typedef __attribute__((ext_vector_type(2))) float float2v;

union u8x16 { short8 v; unsigned short u[8]; };

__device__ __forceinline__ float bits2f(unsigned short u) {
    union { unsigned int i; float f; } c; c.i = ((unsigned int)u) << 16; return c.f;
}
__device__ __forceinline__ unsigned short f2bits(float f) {
    union { float f; unsigned int i; } c; c.f = f;
    unsigned int x = c.i;
    return (unsigned short)((x + 0x7fffu + ((x >> 16) & 1u)) >> 16);   // RNE
}
__device__ __forceinline__ unsigned short f2bits_trunc(float f) {
    union { float f; unsigned int i; } c; c.f = f;
    return (unsigned short)(c.i >> 16);                               // truncate (1 op)
}
__device__ __forceinline__ float2v cvt2(unsigned int w) {
    union { unsigned int i; float f; } lo, hi;
    lo.i = w << 16; hi.i = w & 0xffff0000u;
    return (float2v){lo.f, hi.f};
}
// exact leaky_relu(v) = max(v, 0.2v)
__device__ __forceinline__ float2v lrelu2(float2v v) {
    float2v t = v * 0.2f;
    return (float2v){fmaxf(v.x, t.x), fmaxf(v.y, t.y)};
}

typedef const __attribute__((address_space(1))) void* gvp;
typedef __attribute__((address_space(3))) void* lvp;
__device__ __forceinline__ void gll16(const void* g, void* l) {
    __builtin_amdgcn_global_load_lds((gvp)g, (lvp)l, 16, 0, 0);
}

// ---------------- small utility kernels ----------------
__global__ void zero_int_kernel(int* __restrict__ p, int n) {
    int i = blockIdx.x * blockDim.x + threadIdx.x;
    if (i < n) p[i] = 0;
}

// vectorized f32 -> bf16 (float4 in, ushort4 out; n4 = n/4)
__global__ void convert_bf16_kernel(const float4* __restrict__ src, ushort4* __restrict__ dst, int n4) {
    int i = blockIdx.x * blockDim.x + threadIdx.x;
    if (i < n4) {
        float4 v = src[i];
        ushort4 o;
        o.x = f2bits(v.x); o.y = f2bits(v.y);
        o.z = f2bits(v.z); o.w = f2bits(v.w);
        dst[i] = o;
    }
}

// fused conversion of ALL weights
__global__ void convert_weights_kernel(
    const float* __restrict__ Wl1, const float* __restrict__ Wr1,
    const float* __restrict__ Wl2, const float* __restrict__ Wr2,
    const float* __restrict__ We1, const float* __restrict__ We2,
    const float* __restrict__ bl2, const float* __restrict__ br2,
    unsigned short* __restrict__ wtl1, unsigned short* __restrict__ wtr1,
    unsigned short* __restrict__ wtlr2, unsigned short* __restrict__ weT1,
    unsigned short* __restrict__ weT2, float* __restrict__ blr2) {
    int b = blockIdx.x, tid = threadIdx.x;
    if (b < 1024) {                       // Wl1/Wr1 [128][1024] -> WT [1024][128]
        const float* W = (b < 512) ? Wl1 : Wr1;
        unsigned short* WT = (b < 512) ? wtl1 : wtr1;
        int i = ((b & 511) << 8) + tid;
        int n = i >> 7, k = i & 127;
        WT[i] = f2bits(W[k * 1024 + n]);
    } else if (b < 3072) {                // Wl2/Wr2 [1024][256] -> wtlr2 [512][1024]
        int bb = b - 1024;
        const float* W = (bb < 1024) ? Wl2 : Wr2;
        int i = ((bb & 1023) << 8) + tid;
        int n = i >> 10, k = i & 1023;
        int off = (bb < 1024) ? 0 : 262144;
        wtlr2[off + i] = f2bits(W[k * 256 + n]);
    } else if (b < 3136) {                // We1 [16][1024] -> weT1 [1024][16]
        int i = ((b - 3072) << 8) + tid;
        int col = i >> 4, k = i & 15;
        weT1[i] = f2bits(We1[k * 1024 + col]);
    } else if (b < 3152) {                // We2 [16][256] -> weT2 [256][16]
        int i = ((b - 3136) << 8) + tid;
        int col = i >> 4, k = i & 15;
        weT2[i] = f2bits(We2[k * 256 + col]);
    } else {                              // blr2 = bl2 | br2 (512 f32)
        int i = ((b - 3152) << 8) + tid;
        if (i < 512) blr2[i] = (i < 256) ? bl2[i] : br2[i - 256];
    }
}

// ---------------- bf16 MFMA GEMM (B^T input, async staging, split output) ----
__global__ __launch_bounds__(256) void mfma_gemm_bt_kernel(
    const unsigned short* __restrict__ A, const unsigned short* __restrict__ WT,
    const float* __restrict__ bias, const float* __restrict__ bias2,
    unsigned short* __restrict__ C, unsigned short* __restrict__ C2,
    int M, int K, int Nout) {
    __shared__ unsigned short As[128 * 32];
    __shared__ unsigned short Bs[128 * 32];
    int tid = threadIdx.x;
    int lane = tid & 63, wid = tid >> 6;
    int gm0 = blockIdx.y * 128, gn0 = blockIdx.x * 128;
    int wm = (wid & 1) * 64, wn = (wid >> 1) * 64;
    int l15 = lane & 15, quad = lane >> 4;
    int r0 = wid * 32;
    int gr = r0 + (lane >> 2);
    int kc = (lane & 3) * 8;

    floatx4 acc[4][4];
#pragma unroll
    for (int i = 0; i < 4; i++)
#pragma unroll
        for (int j = 0; j < 4; j++)
#pragma unroll
            for (int r = 0; r < 4; r++) acc[i][j][r] = 0.f;

    const unsigned short* Ap0 = &A[(size_t)(gm0 + gr) * K + kc];
    const unsigned short* Ap1 = Ap0 + (size_t)16 * K;
    const unsigned short* Bp0 = &WT[(size_t)(gn0 + gr) * K + kc];
    const unsigned short* Bp1 = Bp0 + (size_t)16 * K;
    unsigned short* as0 = &As[r0 * 32];
    unsigned short* as1 = &As[(r0 + 16) * 32];
    unsigned short* bs0 = &Bs[r0 * 32];
    unsigned short* bs1 = &Bs[(r0 + 16) * 32];

    for (int k0 = 0; k0 < K; k0 += 32) {
        __syncthreads();
        gll16(Ap0 + k0, as0);
        gll16(Ap1 + k0, as1);
        gll16(Bp0 + k0, bs0);
        gll16(Bp1 + k0, bs1);
        __syncthreads();
        short8 af[4], bfr[4];
#pragma unroll
        for (int i = 0; i < 4; i++)
            af[i] = *(const short8*)&As[(wm + 16 * i + l15) * 32 + quad * 8];
#pragma unroll
        for (int j = 0; j < 4; j++)
            bfr[j] = *(const short8*)&Bs[(wn + 16 * j + l15) * 32 + quad * 8];
#pragma unroll
        for (int i = 0; i < 4; i++)
#pragma unroll
            for (int j = 0; j < 4; j++)
                acc[i][j] = __builtin_amdgcn_mfma_f32_16x16x32_bf16(af[i], bfr[j], acc[i][j], 0, 0, 0);
    }

    unsigned short* Cw = C;
    const float* bp = bias;
    int colb = gn0 + wn + l15;
    if (gn0 >= Nout) { Cw = C2; bp = bias2; colb -= Nout; }
#pragma unroll
    for (int i = 0; i < 4; i++) {
#pragma unroll
        for (int j = 0; j < 4; j++) {
            int col = colb + 16 * j;
            float bv = bp[col];
#pragma unroll
            for (int r = 0; r < 4; r++) {
                int rrow = gm0 + wm + 16 * i + quad * 4 + r;
                Cw[(size_t)rrow * Nout + col] = f2bits(acc[i][j][r] + bv);
            }
        }
    }
}

// ---------------- CSR build ----------------
__global__ void hist_kernel(const int* __restrict__ ei, int* __restrict__ counts, int E) {
    int e = blockIdx.x * blockDim.x + threadIdx.x;
    if (e < E) atomicAdd(&counts[ei[E + e]], 1);
}

// parallel 3-phase exclusive scan of counts[N] (N = 195*256)
__global__ __launch_bounds__(256) void block_sum_kernel(
    const int* __restrict__ counts, int* __restrict__ bsum) {
    int t = threadIdx.x;
    int v = counts[blockIdx.x * 256 + t];
#pragma unroll
    for (int off = 32; off > 0; off >>= 1) v += __shfl_xor(v, off, 64);
    __shared__ int red[4];
    if ((t & 63) == 0) red[t >> 6] = v;
    __syncthreads();
    if (t == 0) bsum[blockIdx.x] = red[0] + red[1] + red[2] + red[3];
}

__global__ __launch_bounds__(256) void bsum_scan_kernel(
    const int* __restrict__ bsum, int* __restrict__ bofs,
    int* __restrict__ offsets, int NBL, int N) {
    __shared__ int tmp[256];
    int t = threadIdx.x;
    int v = (t < NBL) ? bsum[t] : 0;
    tmp[t] = v;
    __syncthreads();
    for (int off = 1; off < 256; off <<= 1) {
        int x = (t >= off) ? tmp[t - off] : 0;
        __syncthreads();
        tmp[t] += x;
        __syncthreads();
    }
    if (t < NBL) bofs[t] = tmp[t] - v;          // exclusive
    if (t == 255) offsets[N] = tmp[255];        // total = E
}

__global__ __launch_bounds__(256) void local_scan_kernel(
    const int* __restrict__ counts, const int* __restrict__ bofs,
    int* __restrict__ offsets, int* __restrict__ woff) {
    __shared__ int tmp[256];
    int t = threadIdx.x;
    int i = blockIdx.x * 256 + t;
    int v = counts[i];
    tmp[t] = v;
    __syncthreads();
    for (int off = 1; off < 256; off <<= 1) {
        int x = (t >= off) ? tmp[t - off] : 0;
        __syncthreads();
        tmp[t] += x;
        __syncthreads();
    }
    int excl = tmp[t] - v + bofs[blockIdx.x];
    offsets[i] = excl;
    woff[i] = excl;
}

__global__ void scatter_kernel(const int* __restrict__ ei, int* __restrict__ woff,
                               int* __restrict__ perm, int* __restrict__ srcs,
                               int* __restrict__ dsts, int E) {
    int e = blockIdx.x * blockDim.x + threadIdx.x;
    if (e < E) {
        int d = ei[E + e];
        int slot = atomicAdd(&woff[d], 1);
        perm[slot] = e;
        srcs[slot] = ei[e];
        dsts[slot] = d;
    }
}

// ---------------- edge scoring v18: unified EB=32, CW=256 ----------------
// Both layers: 32 edges/block, two A-frags share every WeT B-load
// (2 MFMA per load), 256-col passes. HC=1024: NP=4 passes, pass p = head p;
// half k=w*2+hf owns edges k*4..k*4+3 (dedup runs of 4). HC=256: NP=1,
// identical to v17. LDS ~17KB -> occupancy unchanged. Logits bitwise
// identical to v16/v17 (same math, same reduction order).
template<int HC>
__global__ __launch_bounds__(256) void edge_score_v18_kernel(
    const unsigned short* __restrict__ xl, const unsigned short* __restrict__ xr,
    int XS, const float* __restrict__ eattr, const unsigned short* __restrict__ WeT,
    const float* __restrict__ att, const int* __restrict__ perm,
    const int* __restrict__ srcs, const int* __restrict__ dsts,
    float* __restrict__ logits, int E) {
    constexpr int EB = 32;
    constexpr int CW = 256;
    constexpr int NP = HC / CW;                    // 4 (L1) or 1 (L2)
    constexpr int LDE = CW + 8;
    __shared__ unsigned short ef_s[EB * LDE];
    __shared__ int src_s[EB], dst_s[EB], e_s[EB];
    __shared__ float logit_s[EB * 4];

    int tid = threadIdx.x;
    int s0 = blockIdx.x * EB;
    int lane = tid & 63, w = tid >> 6;
    int l15 = lane & 15, quad = lane >> 4;
    int hf = lane >> 5, q = lane & 31;

    if (tid < EB) { src_s[tid] = srcs[s0 + tid]; dst_s[tid] = dsts[s0 + tid]; e_s[tid] = perm[s0 + tid]; }
    __syncthreads();

    // two A-frags: eattr rows for edges 0-15 and 16-31 (K zero-padded 16->32)
    u8x16 a0f, a1f;
    if (quad < 2) {
        const float* ap = &eattr[(size_t)e_s[l15] * 16 + quad * 8];
        float4 a0 = *(const float4*)ap;
        float4 a1 = *(const float4*)(ap + 4);
        a0f.u[0] = f2bits_trunc(a0.x); a0f.u[1] = f2bits_trunc(a0.y);
        a0f.u[2] = f2bits_trunc(a0.z); a0f.u[3] = f2bits_trunc(a0.w);
        a0f.u[4] = f2bits_trunc(a1.x); a0f.u[5] = f2bits_trunc(a1.y);
        a0f.u[6] = f2bits_trunc(a1.z); a0f.u[7] = f2bits_trunc(a1.w);
        const float* bp = &eattr[(size_t)e_s[16 + l15] * 16 + quad * 8];
        float4 b0 = *(const float4*)bp;
        float4 b1 = *(const float4*)(bp + 4);
        a1f.u[0] = f2bits_trunc(b0.x); a1f.u[1] = f2bits_trunc(b0.y);
        a1f.u[2] = f2bits_trunc(b0.z); a1f.u[3] = f2bits_trunc(b0.w);
        a1f.u[4] = f2bits_trunc(b1.x); a1f.u[5] = f2bits_trunc(b1.y);
        a1f.u[6] = f2bits_trunc(b1.z); a1f.u[7] = f2bits_trunc(b1.w);
    } else {
#pragma unroll
        for (int j = 0; j < 8; j++) { a0f.u[j] = 0; a1f.u[j] = 0; }
    }

#pragma unroll
    for (int p = 0; p < NP; p++) {
        // Phase 1: ef[:, p*CW .. +CW) = eattr @ We -> LDS (bf16 trunc)
        // one WeT B-load feeds two MFMAs (rows 0-15 and 16-31)
        for (int t = w; t < CW / 16; t += 4) {
            int colg = p * CW + t * 16 + l15;
            u8x16 b;
            if (quad < 2) *(uint4*)b.u = *(const uint4*)&WeT[(size_t)colg * 16 + quad * 8];
            else {
#pragma unroll
                for (int j = 0; j < 8; j++) b.u[j] = 0;
            }
            floatx4 c = {0.f, 0.f, 0.f, 0.f};
            c = __builtin_amdgcn_mfma_f32_16x16x32_bf16(a0f.v, b.v, c, 0, 0, 0);
#pragma unroll
            for (int r = 0; r < 4; r++)
                ef_s[(quad * 4 + r) * LDE + t * 16 + l15] = f2bits_trunc(c[r]);
            floatx4 c2 = {0.f, 0.f, 0.f, 0.f};
            c2 = __builtin_amdgcn_mfma_f32_16x16x32_bf16(a1f.v, b.v, c2, 0, 0, 0);
#pragma unroll
            for (int r = 0; r < 4; r++)
                ef_s[(16 + quad * 4 + r) * LDE + t * 16 + l15] = f2bits_trunc(c2[r]);
        }
        __syncthreads();

        // Phase 2: half-wave per edge group; lane covers 8 ch (uint4).
        if constexpr (HC == 1024) {
            int k = w * 2 + hf;                // half index 0..7 -> edges k*4..k*4+3
            int c0g = p * 256 + q * 8;         // head p's cols in xl/xr/att
            int c0l = q * 8;                   // col in ef_s
            float2v attv[4];
#pragma unroll
            for (int j = 0; j < 4; j++)
                attv[j] = (float2v){att[c0g + 2 * j], att[c0g + 2 * j + 1]};
            // prefetch the 4 xl gathers (independent, consecutive edges)
            uint4 wlp[4];
#pragma unroll
            for (int pp = 0; pp < 4; pp++)
                wlp[pp] = *(const uint4*)&xl[(size_t)src_s[k * 4 + pp] * XS + c0g];
            int prevd = -1;
            float2v r0, r1, r2, r3;
            r0 = r1 = r2 = r3 = (float2v){0.f, 0.f};
#pragma unroll
            for (int pp = 0; pp < 4; pp++) {
                int e = k * 4 + pp;            // consecutive CSR slots
                int d = dst_s[e];
                if (d != prevd) {              // uniform within 32-lane half
                    uint4 wr = *(const uint4*)&xr[(size_t)d * XS + c0g];
                    r0 = cvt2(wr.x); r1 = cvt2(wr.y); r2 = cvt2(wr.z); r3 = cvt2(wr.w);
                    prevd = d;
                }
                uint4 wf = *(const uint4*)&ef_s[e * LDE + c0l];
                float2v v, p2 = {0.f, 0.f};
                v = cvt2(wlp[pp].x) + r0 + cvt2(wf.x); p2 += attv[0] * lrelu2(v);
                v = cvt2(wlp[pp].y) + r1 + cvt2(wf.y); p2 += attv[1] * lrelu2(v);
                v = cvt2(wlp[pp].z) + r2 + cvt2(wf.z); p2 += attv[2] * lrelu2(v);
                v = cvt2(wlp[pp].w) + r3 + cvt2(wf.w); p2 += attv[3] * lrelu2(v);
                float part = p2.x + p2.y;
                part += __shfl_xor(part, 1, 64);
                part += __shfl_xor(part, 2, 64);
                part += __shfl_xor(part, 4, 64);
                part += __shfl_xor(part, 8, 64);
                part += __shfl_xor(part, 16, 64);
                if (q == 0) logit_s[e * 4 + p] = part;
            }
        } else {
            int c0 = q * 8;                       // all 256 ch over 32 lanes
            int hd = q >> 3;                      // lane's head
            float2v attv[4];
#pragma unroll
            for (int j = 0; j < 4; j++)
                attv[j] = (float2v){att[c0 + 2 * j], att[c0 + 2 * j + 1]};
            uint4 wlp[4];
#pragma unroll
            for (int pp = 0; pp < 4; pp++)
                wlp[pp] = *(const uint4*)&xl[(size_t)src_s[w * 8 + hf * 4 + pp] * XS + c0];
            int prevd = -1;
            float2v r0, r1, r2, r3;
            r0 = r1 = r2 = r3 = (float2v){0.f, 0.f};
#pragma unroll
            for (int pp = 0; pp < 4; pp++) {
                int e = w * 8 + hf * 4 + pp;      // consecutive CSR slots
                int d = dst_s[e];
                if (d != prevd) {                 // uniform within 32-lane half
                    uint4 wr = *(const uint4*)&xr[(size_t)d * XS + c0];
                    r0 = cvt2(wr.x); r1 = cvt2(wr.y); r2 = cvt2(wr.z); r3 = cvt2(wr.w);
                    prevd = d;
                }
                uint4 wf = *(const uint4*)&ef_s[e * LDE + c0];
                float2v v, p2 = {0.f, 0.f};
                v = cvt2(wlp[pp].x) + r0 + cvt2(wf.x); p2 += attv[0] * lrelu2(v);
                v = cvt2(wlp[pp].y) + r1 + cvt2(wf.y); p2 += attv[1] * lrelu2(v);
                v = cvt2(wlp[pp].z) + r2 + cvt2(wf.z); p2 += attv[2] * lrelu2(v);
                v = cvt2(wlp[pp].w) + r3 + cvt2(wf.w); p2 += attv[3] * lrelu2(v);
                float part = p2.x + p2.y;
                part += __shfl_xor(part, 1, 64);
                part += __shfl_xor(part, 2, 64);
                part += __shfl_xor(part, 4, 64);
                if ((q & 7) == 0) logit_s[e * 4 + hd] = part;
            }
        }
        __syncthreads();   // ef_s reuse fence (also logit_s fence on last pass)
    }
    if (tid < EB * 4) logits[(size_t)s0 * 4 + tid] = logit_s[tid];
}

// ---------------- node aggregation: WPN waves per node, 4-unrolled gather ----
template<int HC, int WPN, bool OUT_BF16>
__global__ __launch_bounds__(256) void node_agg_wave_kernel(
    const unsigned short* __restrict__ xl, int XS, const float* __restrict__ logits,
    const int* __restrict__ srcs, const int* __restrict__ offsets,
    const float* __restrict__ bias, void* __restrict__ outv) {
    constexpr int J = HC / (64 * WPN);    // 8 (L1) or 4 (L2)
    int tid = threadIdx.x;
    int wid = tid >> 6, lane = tid & 63;
    int n, ha;
    if constexpr (WPN == 2) { n = blockIdx.x * 2 + (wid >> 1); ha = wid & 1; }
    else { n = blockIdx.x * 4 + wid; ha = 0; }
    int o0 = offsets[n];
    int deg = offsets[n + 1] - o0;

    int hl;
    float m, s;
    if constexpr (WPN == 2) {
        hl = ha * 2 + (lane >> 5);
        int p = lane & 31;
        float lv = (p < deg) ? logits[(size_t)(o0 + p) * 4 + hl] : -3.0e38f;
        m = lv;
        for (int i = p + 32; i < deg; i += 32)              // rare (deg>32)
            m = fmaxf(m, logits[(size_t)(o0 + i) * 4 + hl]);
        m = fmaxf(m, __shfl_xor(m, 1, 64));
        m = fmaxf(m, __shfl_xor(m, 2, 64));
        m = fmaxf(m, __shfl_xor(m, 4, 64));
        m = fmaxf(m, __shfl_xor(m, 8, 64));
        m = fmaxf(m, __shfl_xor(m, 16, 64));
        s = (p < deg) ? __expf(lv - m) : 0.f;
        for (int i = p + 32; i < deg; i += 32)              // rare (deg>32)
            s += __expf(logits[(size_t)(o0 + i) * 4 + hl] - m);
        s += __shfl_xor(s, 1, 64);
        s += __shfl_xor(s, 2, 64);
        s += __shfl_xor(s, 4, 64);
        s += __shfl_xor(s, 8, 64);
        s += __shfl_xor(s, 16, 64);
    } else {
        hl = lane >> 4;
        int p = lane & 15;
        float lv = (p < deg) ? logits[(size_t)(o0 + p) * 4 + hl] : -3.0e38f;
        m = lv;
        for (int i = p + 16; i < deg; i += 16)              // rare (deg>16)
            m = fmaxf(m, logits[(size_t)(o0 + i) * 4 + hl]);
        m = fmaxf(m, __shfl_xor(m, 1, 64));
        m = fmaxf(m, __shfl_xor(m, 2, 64));
        m = fmaxf(m, __shfl_xor(m, 4, 64));
        m = fmaxf(m, __shfl_xor(m, 8, 64));
        s = (p < deg) ? __expf(lv - m) : 0.f;
        for (int i = p + 16; i < deg; i += 16)              // rare (deg>16)
            s += __expf(logits[(size_t)(o0 + i) * 4 + hl] - m);
        s += __shfl_xor(s, 1, 64);
        s += __shfl_xor(s, 2, 64);
        s += __shfl_xor(s, 4, 64);
        s += __shfl_xor(s, 8, 64);
    }
    float inv = 1.f / (s + 1e-16f);

    int c0 = ha * (HC / WPN) + lane * J;
    float acc[J];
#pragma unroll
    for (int v = 0; v < J; v++) acc[v] = bias[c0 + v];

    int i = 0;
    // 4-wide: all gathers issued before exp/fma consumption
    for (; i + 4 <= deg; i += 4) {
        int sl0 = o0 + i, sl1 = o0 + i + 1, sl2 = o0 + i + 2, sl3 = o0 + i + 3;
        int src0 = srcs[sl0], src1 = srcs[sl1], src2 = srcs[sl2], src3 = srcs[sl3];
        if constexpr (J == 8) {
            u8x16 a0, a1, a2, a3;
            a0.v = *(const short8*)&xl[(size_t)src0 * XS + c0];
            a1.v = *(const short8*)&xl[(size_t)src1 * XS + c0];
            a2.v = *(const short8*)&xl[(size_t)src2 * XS + c0];
            a3.v = *(const short8*)&xl[(size_t)src3 * XS + c0];
            float alpha0 = __expf(logits[(size_t)sl0 * 4 + hl] - m) * inv;
            float alpha1 = __expf(logits[(size_t)sl1 * 4 + hl] - m) * inv;
            float alpha2 = __expf(logits[(size_t)sl2 * 4 + hl] - m) * inv;
            float alpha3 = __expf(logits[(size_t)sl3 * 4 + hl] - m) * inv;
#pragma unroll
            for (int v = 0; v < 8; v++) {
                acc[v] += alpha0 * bits2f(a0.u[v]) + alpha1 * bits2f(a1.u[v]);
                acc[v] += alpha2 * bits2f(a2.u[v]) + alpha3 * bits2f(a3.u[v]);
            }
        } else {
            unsigned short u0[4], u1[4], u2[4], u3[4];
            *(ushort4*)u0 = *(const ushort4*)&xl[(size_t)src0 * XS + c0];
            *(ushort4*)u1 = *(const ushort4*)&xl[(size_t)src1 * XS + c0];
            *(ushort4*)u2 = *(const ushort4*)&xl[(size_t)src2 * XS + c0];
            *(ushort4*)u3 = *(const ushort4*)&xl[(size_t)src3 * XS + c0];
            float alpha0 = __expf(logits[(size_t)sl0 * 4 + hl] - m) * inv;
            float alpha1 = __expf(logits[(size_t)sl1 * 4 + hl] - m) * inv;
            float alpha2 = __expf(logits[(size_t)sl2 * 4 + hl] - m) * inv;
            float alpha3 = __expf(logits[(size_t)sl3 * 4 + hl] - m) * inv;
#pragma unroll
            for (int v = 0; v < 4; v++) {
                acc[v] += alpha0 * bits2f(u0[v]) + alpha1 * bits2f(u1[v]);
                acc[v] += alpha2 * bits2f(u2[v]) + alpha3 * bits2f(u3[v]);
            }
        }
    }
    for (; i + 2 <= deg; i += 2) {
        int sl0 = o0 + i, sl1 = o0 + i + 1;
        int src0 = srcs[sl0], src1 = srcs[sl1];
        const unsigned short* row0 = &xl[(size_t)src0 * XS + c0];
        const unsigned short* row1 = &xl[(size_t)src1 * XS + c0];
        float alpha0 = __expf(logits[(size_t)sl0 * 4 + hl] - m) * inv;
        float alpha1 = __expf(logits[(size_t)sl1 * 4 + hl] - m) * inv;
        if constexpr (J == 8) {
            u8x16 a0, a1;
            a0.v = *(const short8*)row0;
            a1.v = *(const short8*)row1;
#pragma unroll
            for (int v = 0; v < 8; v++) acc[v] += alpha0 * bits2f(a0.u[v]) + alpha1 * bits2f(a1.u[v]);
        } else {
            unsigned short u0[4], u1[4];
            *(ushort4*)u0 = *(const ushort4*)row0;
            *(ushort4*)u1 = *(const ushort4*)row1;
#pragma unroll
            for (int v = 0; v < 4; v++) acc[v] += alpha0 * bits2f(u0[v]) + alpha1 * bits2f(u1[v]);
        }
    }
    if (i < deg) {
        int sl = o0 + i;
        float alpha = __expf(logits[(size_t)sl * 4 + hl] - m) * inv;
        int src = srcs[sl];
        const unsigned short* row = &xl[(size_t)src * XS + c0];
        if constexpr (J == 8) {
            u8x16 a0; a0.v = *(const short8*)row;
#pragma unroll
            for (int v = 0; v < 8; v++) acc[v] += alpha * bits2f(a0.u[v]);
        } else {
            unsigned short us[4];
            *(ushort4*)us = *(const ushort4*)row;
#pragma unroll
            for (int v = 0; v < 4; v++) acc[v] += alpha * bits2f(us[v]);
        }
    }

    if constexpr (OUT_BF16) {
        unsigned short* o = (unsigned short*)outv;
        u8x16 w0;
#pragma unroll
        for (int v = 0; v < 8; v++) w0.u[v] = f2bits(fmaxf(acc[v], 0.f));
        *(short8*)&o[(size_t)n * HC + c0] = w0.v;
    } else {
        float* o = (float*)outv;
        float4 f;
        f.x = fmaxf(acc[0], 0.f); f.y = fmaxf(acc[1], 0.f);
        f.z = fmaxf(acc[2], 0.f); f.w = fmaxf(acc[3], 0.f);
        *(float4*)&o[(size_t)n * HC + c0] = f;
    }
}

// ---------------- MLP head ----------------
__global__ __launch_bounds__(64) void mlp_head_kernel(
    const float* __restrict__ h2, const int* __restrict__ nnod,
    const float* __restrict__ w1, const float* __restrict__ b1,
    const float* __restrict__ w2, const float* __restrict__ b2,
    float* __restrict__ out, int B) {
    int b = blockIdx.x, tid = threadIdx.x;
    int sum = 0;
    for (int j = tid; j <= b; j += 64) sum += nnod[j];
#pragma unroll
    for (int off = 32; off > 0; off >>= 1) sum += __shfl_xor(sum, off, 64);
    int node = sum - 1;
    __shared__ float mast[256];
    for (int i = tid; i < 256; i += 64) mast[i] = h2[(size_t)node * 256 + i];
    __syncthreads();
    float z = 0.f;
    for (int k = 0; k < 256; k++) z += mast[k] * w1[k * 64 + tid];
    z += b1[tid];
    z = z > 0.f ? z : 0.f;
    float p = z * w2[tid];
#pragma unroll
    for (int off = 32; off > 0; off >>= 1) p += __shfl_down(p, off, 64);
    if (tid == 0) out[b] = p + b2[0];
}

extern "C" void kernel_launch(void* const* d_in, const int* in_sizes, int n_in,
                              void* d_out, int out_size, void* d_ws, size_t ws_size,
                              hipStream_t stream) {
    const float* x     = (const float*)d_in[0];
    const int*   ei    = (const int*)d_in[1];
    const float* eattr = (const float*)d_in[2];
    const int*   nnod  = (const int*)d_in[3];
    const float* Wl1 = (const float*)d_in[4];
    const float* bl1 = (const float*)d_in[5];
    const float* Wr1 = (const float*)d_in[6];
    const float* br1 = (const float*)d_in[7];
    const float* We1 = (const float*)d_in[8];
    const float* att1= (const float*)d_in[9];
    const float* b1  = (const float*)d_in[10];
    const float* Wl2 = (const float*)d_in[11];
    const float* bl2 = (const float*)d_in[12];
    const float* Wr2 = (const float*)d_in[13];
    const float* br2 = (const float*)d_in[14];
    const float* We2 = (const float*)d_in[15];
    const float* att2= (const float*)d_in[16];
    const float* b2  = (const float*)d_in[17];
    const float* fc1w= (const float*)d_in[18];
    const float* fc1b= (const float*)d_in[19];
    const float* fc2w= (const float*)d_in[20];
    const float* fc2b= (const float*)d_in[21];
    float* out = (float*)d_out;

    const int N = NN, E = EE, B = BB;
    const int NBL = N / 256;            // 195 scan blocks

    // ---------- workspace layout ----------
    char* base = (char*)d_ws;
    const size_t NB1 = (size_t)N * 1024 * 2;
    unsigned short* xl1   = (unsigned short*)base;
    unsigned short* xlxr2 = (unsigned short*)base;                       // [N][512]
    float*          h2    = (float*)(base + (size_t)N * 512 * 2);        // [N][256] f32
    unsigned short* xr1 = (unsigned short*)(base + NB1);
    unsigned short* h1  = (unsigned short*)(base + NB1);
    char* t = base + 2 * NB1;
    float* logits = (float*)t;        t += (size_t)E * 4 * sizeof(float);
    int* counts   = (int*)t;          t += (size_t)N * sizeof(int);
    int* offsets  = (int*)t;          t += (size_t)(N + 1) * sizeof(int);
    int* woff     = (int*)t;          t += (size_t)N * sizeof(int);
    int* perm     = (int*)t;          t += (size_t)E * sizeof(int);
    int* srcs     = (int*)t;          t += (size_t)E * sizeof(int);
    int* dsts     = (int*)t;          t += (size_t)E * sizeof(int);
    int* bsum     = (int*)t;          t += (size_t)256 * sizeof(int);
    int* bofs     = (int*)t;          t += (size_t)256 * sizeof(int);
    t = (char*)(((uintptr_t)t + 63) & ~(uintptr_t)63);
    unsigned short* xb    = (unsigned short*)t; t += (size_t)N * 128 * 2;
    unsigned short* wtl1  = (unsigned short*)t; t += (size_t)1024 * 128 * 2;   // contiguous with
    unsigned short* wtr1  = (unsigned short*)t; t += (size_t)1024 * 128 * 2;   //  wtl1 -> [2048][128]
    unsigned short* wtlr2 = (unsigned short*)t; t += (size_t)512 * 1024 * 2;
    unsigned short* weT1  = (unsigned short*)t; t += (size_t)1024 * 16 * 2;
    unsigned short* weT2  = (unsigned short*)t; t += (size_t)256 * 16 * 2;
    float* blr2           = (float*)t;          t += (size_t)512 * sizeof(float);
    size_t required = (size_t)(t - base);
    if (ws_size < required) return;   // guard: absmax-fail instead of abort

    dim3 blk(256);

    // ---------- CSR build (parallel 3-phase scan) ----------
    zero_int_kernel<<<(N + 255) / 256, blk, 0, stream>>>(counts, N);
    hist_kernel<<<(E + 255) / 256, blk, 0, stream>>>(ei, counts, E);
    block_sum_kernel<<<NBL, blk, 0, stream>>>(counts, bsum);
    bsum_scan_kernel<<<1, blk, 0, stream>>>(bsum, bofs, offsets, NBL, N);
    local_scan_kernel<<<NBL, blk, 0, stream>>>(counts, bofs, offsets, woff);
    scatter_kernel<<<(E + 255) / 256, blk, 0, stream>>>(ei, woff, perm, srcs, dsts, E);

    // ---------- conversions ----------
    convert_bf16_kernel<<<(N * 32 + 255) / 256, blk, 0, stream>>>((const float4*)x, (ushort4*)xb, N * 32);
    convert_weights_kernel<<<3154, blk, 0, stream>>>(Wl1, Wr1, Wl2, Wr2, We1, We2, bl2, br2,
                                                     wtl1, wtr1, wtlr2, weT1, weT2, blr2);

    // ---------- layer 1 (fused xl|xr GEMM, Ntot=2048, split write) ----------
    {
        dim3 g1(2048 / 128, N / 128);
        mfma_gemm_bt_kernel<<<g1, blk, 0, stream>>>(xb, wtl1, bl1, br1, xl1, xr1, N, 128, 1024);
    }
    edge_score_v18_kernel<1024><<<E / 32, blk, 0, stream>>>(xl1, xr1, 1024, eattr, weT1, att1, perm, srcs, dsts, logits, E);
    node_agg_wave_kernel<1024, 2, true><<<N / 2, blk, 0, stream>>>(xl1, 1024, logits, srcs, offsets, b1, h1);

    // ---------- layer 2 (fused xl|xr GEMM, N=512) ----------
    {
        dim3 g2(512 / 128, N / 128);
        mfma_gemm_bt_kernel<<<g2, blk, 0, stream>>>(h1, wtlr2, blr2, blr2, xlxr2, xlxr2, N, 1024, 512);
    }
    edge_score_v18_kernel<256><<<E / 32, blk, 0, stream>>>(xlxr2, xlxr2 + 256, 512, eattr, weT2, att2, perm, srcs, dsts, logits, E);
    node_agg_wave_kernel<256, 1, false><<<N / 4, blk, 0, stream>>>(xlxr2, 512, logits, srcs, offsets, b2, h2);

    // ---------- head ----------
    mlp_head_kernel<<<B, 64, 0, stream>>>(h2, nnod, fc1w, fc1b, fc2w, fc2b, out, B);
}